// Round 5
// baseline (856.106 us; speedup 1.0000x reference)
//
#include <hip/hip_runtime.h>
#include <math.h>

#define NB 4
#define NL 4096
#define NE 512
#define NH 8
#define ND 64
#define NF 2049      // NL/2 + 1
#define WSZ (NE * NE) // 262144 elements per weight matrix
#define QPAD 2176    // q rows padded to 17*128 (grid extent!)
#define OPSZ ((long)NB * NH * QPAD * 64)   // one half-partial component

static constexpr float INV_SQRT_N = 1.0f / 64.0f;   // 1/sqrt(4096), ortho norm

typedef __attribute__((ext_vector_type(8))) short bf16x8;
typedef __attribute__((ext_vector_type(4))) short short4v;
typedef __attribute__((ext_vector_type(4))) float f32x4;

__device__ __forceinline__ float2 cmul(float2 a, float2 b) {
    return make_float2(a.x * b.x - a.y * b.y, a.x * b.y + a.y * b.x);
}

__device__ __forceinline__ short cvt_bf16(float f) {
    unsigned u = __float_as_uint(f);
    unsigned r = (u + 0x7FFFu + ((u >> 16) & 1u)) >> 16;
    return (short)r;
}

__device__ __forceinline__ int pack_bf16x2(float a, float b) {
    return (int)(unsigned short)cvt_bf16(a) | ((int)(unsigned short)cvt_bf16(b) << 16);
}

__device__ __forceinline__ float2 unpk(int v) {
    return make_float2(__uint_as_float(((unsigned)v & 0xffffu) << 16),
                       __uint_as_float((unsigned)v & 0xffff0000u));
}

// base-4 digit reversal of a 12-bit index
__device__ __forceinline__ int b4rev(int t) {
    int r = __brev((unsigned)t) >> 20;
    return ((r & 0x555) << 1) | ((r & 0xAAA) >> 1);
}

// ---------------- one-time exact twiddles ----------------
__global__ __launch_bounds__(256) void twiddle_kernel(float2* __restrict__ twg) {
    int j = blockIdx.x * 256 + threadIdx.x;
    double ang = (2.0 * M_PI / (double)NL) * (double)j;
    double s, c;
    sincos(ang, &s, &c);
    twg[j] = make_float2((float)c, (float)s);
}

// ---------------- one-time weight cast fp32 -> bf16 (7 matrices) ----------------
__global__ __launch_bounds__(256) void castw_kernel(
    const float* __restrict__ w0, const float* __restrict__ w1,
    const float* __restrict__ w2, const float* __restrict__ w3,
    const float* __restrict__ w4, const float* __restrict__ w5,
    const float* __restrict__ w6, short* __restrict__ dst) {
    int which = blockIdx.y;
    const float* s = which == 0 ? w0 : which == 1 ? w1 : which == 2 ? w2 :
                     which == 3 ? w3 : which == 4 ? w4 : which == 5 ? w5 : w6;
    long i = (long)blockIdx.x * 1024 + threadIdx.x * 4;
    float4 v = *(const float4*)(s + i);
    short4v o = {cvt_bf16(v.x), cvt_bf16(v.y), cvt_bf16(v.z), cvt_bf16(v.w)};
    *(short4v*)(dst + (long)which * WSZ + i) = o;
}

// ---------------- LayerNorm: one row (512) per wave, bf16 output ----------------
__global__ __launch_bounds__(256) void ln_kernel(
    const float* __restrict__ x, const float* __restrict__ g,
    const float* __restrict__ be, short* __restrict__ xnb) {
    int wv = threadIdx.x >> 6, lane = threadIdx.x & 63;
    long row = (long)blockIdx.x * 4 + wv;
    const float* xp = x + row * NE + lane * 8;
    float4 a = *(const float4*)xp;
    float4 b = *(const float4*)(xp + 4);
    float s  = a.x + a.y + a.z + a.w + b.x + b.y + b.z + b.w;
    float ss = a.x * a.x + a.y * a.y + a.z * a.z + a.w * a.w
             + b.x * b.x + b.y * b.y + b.z * b.z + b.w * b.w;
#pragma unroll
    for (int o = 32; o; o >>= 1) { s += __shfl_xor(s, o); ss += __shfl_xor(ss, o); }
    float mu = s * (1.0f / NE);
    float var = ss * (1.0f / NE) - mu * mu;
    float rs = rsqrtf(var + 1e-5f);
    const float* gp = g + lane * 8;
    const float* bp = be + lane * 8;
    float4 g0 = *(const float4*)gp, g1 = *(const float4*)(gp + 4);
    float4 b0 = *(const float4*)bp, b1 = *(const float4*)(bp + 4);
    bf16x8 ov;
    ov[0] = cvt_bf16((a.x - mu) * rs * g0.x + b0.x);
    ov[1] = cvt_bf16((a.y - mu) * rs * g0.y + b0.y);
    ov[2] = cvt_bf16((a.z - mu) * rs * g0.z + b0.z);
    ov[3] = cvt_bf16((a.w - mu) * rs * g0.w + b0.w);
    ov[4] = cvt_bf16((b.x - mu) * rs * g1.x + b1.x);
    ov[5] = cvt_bf16((b.y - mu) * rs * g1.y + b1.y);
    ov[6] = cvt_bf16((b.z - mu) * rs * g1.z + b1.z);
    ov[7] = cvt_bf16((b.w - mu) * rs * g1.w + b1.w);
    *(bf16x8*)(xnb + row * NE + lane * 8) = ov;
}

// ---------------- radix-4 FFT stages in LDS (4096 pts, 6 stages) ----------------
template <int INV>
__device__ __forceinline__ void fft4_stages(float2* sdata, const float2* tws, int tid) {
#pragma unroll
    for (int st = 0; st < 6; ++st) {
        __syncthreads();
        int Q = 1 << (2 * st);
        int tq = 10 - 2 * st;
#pragma unroll
        for (int jj = 0; jj < 4; ++jj) {
            int j = tid + jj * 256;
            int k = j & (Q - 1);
            int i0 = ((j >> (2 * st)) << (2 * st + 2)) | k;
            float2 w1 = tws[k << tq];
            float2 w2 = tws[(2 * k) << tq];
            float2 w3 = cmul(w1, w2);
            float2 a = sdata[i0];
            float2 b = cmul(w1, sdata[i0 + Q]);
            float2 c = cmul(w2, sdata[i0 + 2 * Q]);
            float2 d = cmul(w3, sdata[i0 + 3 * Q]);
            float2 t0 = make_float2(a.x + c.x, a.y + c.y);
            float2 t1 = make_float2(a.x - c.x, a.y - c.y);
            float2 t2 = make_float2(b.x + d.x, b.y + d.y);
            float2 bd = make_float2(b.x - d.x, b.y - d.y);
            float2 t3 = INV ? make_float2(-bd.y, bd.x) : make_float2(bd.y, -bd.x);
            sdata[i0]         = make_float2(t0.x + t2.x, t0.y + t2.y);
            sdata[i0 + Q]     = make_float2(t1.x + t3.x, t1.y + t3.y);
            sdata[i0 + 2 * Q] = make_float2(t0.x - t2.x, t0.y - t2.y);
            sdata[i0 + 3 * Q] = make_float2(t1.x - t3.x, t1.y - t3.y);
        }
    }
    __syncthreads();
}

// XCD-aware e-pair swizzle: consecutive dispatch ids (round-robin over 8 XCDs)
// map to e-stripes 32 pairs apart, so each XCD owns a contiguous 64-column band.
__device__ __forceinline__ int ep_swizzle(int loc) {
    return ((loc & 7) << 5) | (loc >> 3);
}

// ---------------- forward rfft: 2 real bf16 columns in 1 complex FFT ----------------
__global__ __launch_bounds__(256) void rfft_pair(
    const short* __restrict__ xnb, const float2* __restrict__ twg,
    short* __restrict__ xr, short* __restrict__ xi) {
    __shared__ float2 sdata[NL];
    __shared__ float2 tws[NL / 2];
    int b = blockIdx.x >> 8;
    int e0 = ep_swizzle(blockIdx.x & 255) * 2;
    int tid = threadIdx.x;
    const short* xp = xnb + (long)b * NL * NE + e0;
#pragma unroll
    for (int jj = 0; jj < 16; ++jj) {
        int t = tid + jj * 256;
        int v = *(const int*)(xp + (long)t * NE);
        sdata[b4rev(t)] = unpk(v);
    }
#pragma unroll
    for (int jj = 0; jj < 8; ++jj) {
        int j = tid + jj * 256;
        float2 w = twg[j];
        tws[j] = make_float2(w.x, -w.y);   // forward: e^{-i theta}
    }
    fft4_stages<0>(sdata, tws, tid);
    short* xrp = xr + (long)b * NF * NE + e0;
    short* xip = xi + (long)b * NF * NE + e0;
    for (int f = tid; f < NF; f += 256) {
        int M = (NL - f) & (NL - 1);
        float2 zf = sdata[f], zm = sdata[M];
        float re0 = (zf.x + zm.x) * (0.5f * INV_SQRT_N);
        float im0 = (zf.y - zm.y) * (0.5f * INV_SQRT_N);
        float re1 = (zf.y + zm.y) * (0.5f * INV_SQRT_N);
        float im1 = (zm.x - zf.x) * (0.5f * INV_SQRT_N);
        *(int*)(xrp + (long)f * NE) = pack_bf16x2(re0, re1);
        *(int*)(xip + (long)f * NE) = pack_bf16x2(im0, im1);
    }
}

// ---------------- inverse rfft: bf16 in, bf16 out ----------------
__global__ __launch_bounds__(256) void irfft_pair(
    const short* __restrict__ orr, const short* __restrict__ oii,
    const float2* __restrict__ twg, short* __restrict__ yt) {
    __shared__ float2 sdata[NL];
    __shared__ float2 tws[NL / 2];
    int b = blockIdx.x >> 8;
    int e0 = ep_swizzle(blockIdx.x & 255) * 2;
    int tid = threadIdx.x;
    const short* orp = orr + (long)b * NF * NE + e0;
    const short* oip = oii + (long)b * NF * NE + e0;
    for (int f = tid; f < NF; f += 256) {
        float2 vr = unpk(*(const int*)(orp + (long)f * NE));  // (O0r, O1r)
        float2 vi = unpk(*(const int*)(oip + (long)f * NE));  // (O0i, O1i)
        if (f == 0 || f == NL / 2) vi = make_float2(0.f, 0.f);  // C2R ignores these
        sdata[b4rev(f)] = make_float2(vr.x - vi.y, vi.x + vr.y);
        if (f > 0 && f < NL / 2) {
            sdata[b4rev(NL - f)] = make_float2(vr.x + vi.y, vr.y - vi.x);
        }
    }
#pragma unroll
    for (int jj = 0; jj < 8; ++jj) {
        int j = tid + jj * 256;
        tws[j] = twg[j];                   // inverse: e^{+i theta}
    }
    fft4_stages<1>(sdata, tws, tid);
    short* yp = yt + (long)b * NL * NE + e0;
#pragma unroll
    for (int jj = 0; jj < 16; ++jj) {
        int t = tid + jj * 256;
        float2 z = sdata[t];
        *(int*)(yp + (long)t * NE) = pack_bf16x2(z.x * INV_SQRT_N, z.y * INV_SQRT_N);
    }
}

// ---------------- bf16 MFMA GEMM core ----------------
__device__ __forceinline__ void gemm_core(
    const short* __restrict__ A, const short* __restrict__ W,
    const float* __restrict__ bias, float scale, short* __restrict__ Cb,
    float* __restrict__ Cf, int N) {
    __shared__ short As[128][40];
    __shared__ short Bs[128][40];
    int o0 = blockIdx.x * 128;
    int n0 = blockIdx.y * 128;
    int tid = threadIdx.x;
    int lane = tid & 63, wv = tid >> 6;
    int quad = lane >> 4, cl = lane & 15;
    int rbase = (wv >> 1) << 6;
    int cbase = (wv & 1) << 6;
    int srow = tid >> 2;    // 0..63
    int sseg = tid & 3;     // 0..3
    f32x4 acc[4][4];
#pragma unroll
    for (int i = 0; i < 4; ++i)
#pragma unroll
        for (int j = 0; j < 4; ++j) acc[i][j] = (f32x4){0, 0, 0, 0};

    int ra = n0 + srow;      if (ra >= N) ra = N - 1;
    int rb = n0 + srow + 64; if (rb >= N) rb = N - 1;
    const short* Ap0 = A + (long)ra * NE + sseg * 8;
    const short* Ap1 = A + (long)rb * NE + sseg * 8;
    const short* Wp0 = W + (long)(o0 + srow) * NE + sseg * 8;
    const short* Wp1 = W + (long)(o0 + srow + 64) * NE + sseg * 8;

    bf16x8 a0 = *(const bf16x8*)Ap0, a1 = *(const bf16x8*)Ap1;
    bf16x8 b0 = *(const bf16x8*)Wp0, b1 = *(const bf16x8*)Wp1;

    for (int kt = 0; kt < 16; ++kt) {
        __syncthreads();
        *(bf16x8*)&As[srow][sseg * 8] = a0;
        *(bf16x8*)&As[srow + 64][sseg * 8] = a1;
        *(bf16x8*)&Bs[srow][sseg * 8] = b0;
        *(bf16x8*)&Bs[srow + 64][sseg * 8] = b1;
        __syncthreads();
        if (kt < 15) {
            int ko = (kt + 1) * 32;
            a0 = *(const bf16x8*)(Ap0 + ko);
            a1 = *(const bf16x8*)(Ap1 + ko);
            b0 = *(const bf16x8*)(Wp0 + ko);
            b1 = *(const bf16x8*)(Wp1 + ko);
        }
        bf16x8 ar[4], br[4];
#pragma unroll
        for (int i = 0; i < 4; ++i) ar[i] = *(const bf16x8*)&As[rbase + 16 * i + cl][quad * 8];
#pragma unroll
        for (int j = 0; j < 4; ++j) br[j] = *(const bf16x8*)&Bs[cbase + 16 * j + cl][quad * 8];
#pragma unroll
        for (int i = 0; i < 4; ++i)
#pragma unroll
            for (int j = 0; j < 4; ++j)
                acc[i][j] = __builtin_amdgcn_mfma_f32_16x16x32_bf16(ar[i], br[j], acc[i][j], 0, 0, 0);
    }
    float bv[4];
#pragma unroll
    for (int j = 0; j < 4; ++j) bv[j] = bias ? bias[o0 + cbase + 16 * j + cl] : 0.0f;
#pragma unroll
    for (int i = 0; i < 4; ++i) {
#pragma unroll
        for (int r = 0; r < 4; ++r) {
            int n = n0 + rbase + 16 * i + quad * 4 + r;
            if (n >= N) continue;
#pragma unroll
            for (int j = 0; j < 4; ++j) {
                float v = (acc[i][j][r] + bv[j]) * scale;
                int o = o0 + cbase + 16 * j + cl;
                if (Cb) Cb[(long)n * NE + o] = cvt_bf16(v);
                else    Cf[(long)n * NE + o] = v;
            }
        }
    }
}

__global__ __launch_bounds__(256) void gemm_qkv(
    const short* __restrict__ A,
    const short* __restrict__ W0, const short* __restrict__ W1, const short* __restrict__ W2,
    const float* __restrict__ b0, const float* __restrict__ b1, const float* __restrict__ b2,
    short* __restrict__ C0, short* __restrict__ C1, short* __restrict__ C2, int N) {
    int z = blockIdx.z;
    const short* W = z == 0 ? W0 : z == 1 ? W1 : W2;
    const float* bb = z == 0 ? b0 : z == 1 ? b1 : b2;
    short* C = z == 0 ? C0 : z == 1 ? C1 : C2;
    gemm_core(A, W, bb, z == 0 ? 0.125f : 1.0f, C, nullptr, N);
}

__global__ __launch_bounds__(256) void gemm_out(
    const short* __restrict__ A, const short* __restrict__ W,
    float* __restrict__ C, int N) {
    gemm_core(A, W, nullptr, 1.0f, nullptr, C, N);
}

// ---------------- MFMA flash attention: register-resident P (S^T trick) ----------------
// S^T = K.Q^T via mfma_16x16x32 (C rows = key, cols = q). Its C-layout IS the
// B-operand layout of mfma_16x16x16bf16_1k, so P never touches LDS:
// O^T = V^T.P^T accumulated per 16-d tile. l is per-lane (q=lane&15).
// Vt swizzled at 4-short granularity: col-group g' = g ^ ((d>>2)&15).
// R1: 128 q-rows per block (2 q-subtiles u=0,1 per wave).
// R3: KEY-SPLIT (flash-decoding): blockIdx.z = b*2+half; each block does half
// the K/V tiles (17 or 16) and writes UNNORMALIZED fp32 partial O + partial l.
// Doubles grid to 1088 blocks -> 4.25 waves/SIMD (was 2.1): latency cover.
// R4 fix: QPAD must be 17*128=2176 (grid q-extent, was 2112 -> OOB corruption);
// partial writes additionally guarded q < NF.
__global__ __launch_bounds__(256, 4) void fattn_mfma(
    const short* __restrict__ Qr, const short* __restrict__ Qi,
    const short* __restrict__ Kr, const short* __restrict__ Ki,
    const short* __restrict__ Vr, const short* __restrict__ Vi,
    float* __restrict__ Opr, float* __restrict__ Opi, float* __restrict__ lsp) {
    __shared__ short Ks[2][64][72];   // [r/i][key][d]
    __shared__ short Vt[2][64][72];   // [r/i][d][key 4-swizzled]
    int tid = threadIdx.x;
    int wv = tid >> 6, lane = tid & 63;
    int quad = lane >> 4, cl = lane & 15;
    int h = blockIdx.y;
    int zz = blockIdx.z;
    int b = zz >> 1, half = zz & 1;
    long base = (long)b * NF * NE + h * ND;
    int qbase = blockIdx.x * 128 + wv * 32;
    int kt0 = half * 17;
    int ktN = half ? 33 : 17;

    int sk0 = (tid >> 4) << 2;   // staged keys (group g0 = tid>>4)
    int sd0 = (tid & 15) << 2;   // staged dims
    int g0 = tid >> 4;
    int dsw = tid & 15;          // (d>>2) for all 4 staged dim rows

    // ---- Q fragments: B-operand of S^T (B[k=d][n=q]), pre-scaled by 1/8 ----
    bf16x8 qar[2][2], qai[2][2];
#pragma unroll
    for (int u = 0; u < 2; ++u) {
        int qrow = qbase + 16 * u + cl; if (qrow >= NF) qrow = NF - 1;
        const short* pr = Qr + base + (long)qrow * NE + 8 * quad;
        const short* pi = Qi + base + (long)qrow * NE + 8 * quad;
        qar[u][0] = *(const bf16x8*)pr;
        qar[u][1] = *(const bf16x8*)(pr + 32);
        qai[u][0] = *(const bf16x8*)pi;
        qai[u][1] = *(const bf16x8*)(pi + 32);
    }

    float ls[2] = {0.f, 0.f};
    f32x4 Or2[4][2], Oi2[4][2];   // O^T tiles: rows d=16nt+quad*4+r, col q=16u+cl
#pragma unroll
    for (int t = 0; t < 4; ++t)
#pragma unroll
        for (int u = 0; u < 2; ++u) {
            Or2[t][u] = (f32x4){0, 0, 0, 0};
            Oi2[t][u] = (f32x4){0, 0, 0, 0};
        }

    short4v lk0[4], lk1[4], lv0[4], lv1[4];
    const long TSTEP = (long)64 * NE;
    const short* pKr = Kr + base + (long)sk0 * NE + sd0 + (long)kt0 * TSTEP;
    const short* pKi = Ki + base + (long)sk0 * NE + sd0 + (long)kt0 * TSTEP;
    const short* pVr = Vr + base + (long)sk0 * NE + sd0 + (long)kt0 * TSTEP;
    const short* pVi = Vi + base + (long)sk0 * NE + sd0 + (long)kt0 * TSTEP;

    auto ldfull = [&]() {
#pragma unroll
        for (int kk = 0; kk < 4; ++kk) {
            long o = (long)kk * NE;
            lk0[kk] = *(const short4v*)(pKr + o);
            lk1[kk] = *(const short4v*)(pKi + o);
            lv0[kk] = *(const short4v*)(pVr + o);
            lv1[kk] = *(const short4v*)(pVi + o);
        }
        pKr += TSTEP; pKi += TSTEP; pVr += TSTEP; pVi += TSTEP;
    };
    auto ldmask = [&]() {   // tile 32: keys 2048..2111, mask >= NF
        short4v z4 = {0, 0, 0, 0};
#pragma unroll
        for (int kk = 0; kk < 4; ++kk) {
            int mg = 2048 + sk0 + kk;
            if (mg < NF) {
                long o = (long)kk * NE;
                lk0[kk] = *(const short4v*)(pKr + o);
                lk1[kk] = *(const short4v*)(pKi + o);
                lv0[kk] = *(const short4v*)(pVr + o);
                lv1[kk] = *(const short4v*)(pVi + o);
            } else { lk0[kk] = z4; lk1[kk] = z4; lv0[kk] = z4; lv1[kk] = z4; }
        }
    };
    ldfull();   // regs <- tile kt0

    for (int kt = kt0; kt < ktN; ++kt) {
        __syncthreads();
        // ---- stage K (row-major) + V (transposed, 4-granular XOR swizzle) ----
#pragma unroll
        for (int kk = 0; kk < 4; ++kk) {
            *(short4v*)&Ks[0][sk0 + kk][sd0] = lk0[kk];
            *(short4v*)&Ks[1][sk0 + kk][sd0] = lk1[kk];
        }
        {
            int cv = (g0 ^ dsw) << 2;
#pragma unroll
            for (int dd = 0; dd < 4; ++dd) {
                short4v t0 = {lv0[0][dd], lv0[1][dd], lv0[2][dd], lv0[3][dd]};
                *(short4v*)&Vt[0][sd0 + dd][cv] = t0;
                short4v t1 = {lv1[0][dd], lv1[1][dd], lv1[2][dd], lv1[3][dd]};
                *(short4v*)&Vt[1][sd0 + dd][cv] = t1;
            }
        }
        __syncthreads();
        if (kt + 1 < ktN) {                 // prefetch next tile into regs
            if (kt + 1 < 32) ldfull();
            else ldmask();
        }

        // ---- S^T = K.Q^T (32 MFMAs): c[t][u] rows = key quad*4+r, col = q ----
        f32x4 c[4][2];
        __builtin_amdgcn_s_setprio(1);
#pragma unroll
        for (int t = 0; t < 4; ++t) {
            const short* kr = &Ks[0][cl + 16 * t][8 * quad];
            const short* ki = &Ks[1][cl + 16 * t][8 * quad];
            bf16x8 k0 = *(const bf16x8*)kr;
            bf16x8 k1 = *(const bf16x8*)(kr + 32);
            bf16x8 k2 = *(const bf16x8*)ki;
            bf16x8 k3 = *(const bf16x8*)(ki + 32);
#pragma unroll
            for (int u = 0; u < 2; ++u) {
                f32x4 acc = (f32x4){0, 0, 0, 0};
                acc = __builtin_amdgcn_mfma_f32_16x16x32_bf16(k0, qar[u][0], acc, 0, 0, 0);
                acc = __builtin_amdgcn_mfma_f32_16x16x32_bf16(k1, qar[u][1], acc, 0, 0, 0);
                acc = __builtin_amdgcn_mfma_f32_16x16x32_bf16(k2, qai[u][0], acc, 0, 0, 0);
                acc = __builtin_amdgcn_mfma_f32_16x16x32_bf16(k3, qai[u][1], acc, 0, 0, 0);
                c[t][u] = acc;
            }
        }
        __builtin_amdgcn_s_setprio(0);

        // ---- exp (no max-sub: |s|<~5), per-lane l, pack B-operands ----
        short4v pb[4][2];
        if (kt < 32) {   // all 64 keys valid: branch-free
#pragma unroll
            for (int t = 0; t < 4; ++t)
#pragma unroll
                for (int u = 0; u < 2; ++u) {
                    float p0 = __expf(c[t][u][0]);
                    float p1 = __expf(c[t][u][1]);
                    float p2 = __expf(c[t][u][2]);
                    float p3 = __expf(c[t][u][3]);
                    ls[u] += (p0 + p1) + (p2 + p3);
                    pb[t][u] = (short4v){cvt_bf16(p0), cvt_bf16(p1),
                                         cvt_bf16(p2), cvt_bf16(p3)};
                }
        } else {         // tail tile: mask keys >= NF
#pragma unroll
            for (int t = 0; t < 4; ++t) {
                int kbase = 2048 + 16 * t + quad * 4;
#pragma unroll
                for (int u = 0; u < 2; ++u) {
                    float p0 = (kbase + 0 < NF) ? __expf(c[t][u][0]) : 0.0f;
                    float p1 = (kbase + 1 < NF) ? __expf(c[t][u][1]) : 0.0f;
                    float p2 = (kbase + 2 < NF) ? __expf(c[t][u][2]) : 0.0f;
                    float p3 = (kbase + 3 < NF) ? __expf(c[t][u][3]) : 0.0f;
                    ls[u] += (p0 + p1) + (p2 + p3);
                    pb[t][u] = (short4v){cvt_bf16(p0), cvt_bf16(p1),
                                         cvt_bf16(p2), cvt_bf16(p3)};
                }
            }
        }

        // ---- O^T += V^T.P^T  (64 mfma_16x16x16, P in registers) ----
        __builtin_amdgcn_s_setprio(1);
#pragma unroll
        for (int nt = 0; nt < 4; ++nt) {
            int d = cl + 16 * nt;
            int dg = (d >> 2) & 15;
#pragma unroll
            for (int t = 0; t < 4; ++t) {
                int g = 4 * t + quad;
                int cv = ((g ^ dg) << 2);
                short4v va = *(const short4v*)&Vt[0][d][cv];
                short4v vb = *(const short4v*)&Vt[1][d][cv];
#pragma unroll
                for (int u = 0; u < 2; ++u) {
                    Or2[nt][u] = __builtin_amdgcn_mfma_f32_16x16x16bf16_1k(va, pb[t][u], Or2[nt][u], 0, 0, 0);
                    Oi2[nt][u] = __builtin_amdgcn_mfma_f32_16x16x16bf16_1k(vb, pb[t][u], Oi2[nt][u], 0, 0, 0);
                }
            }
        }
        __builtin_amdgcn_s_setprio(0);
    }

    // ---- l reduce over quads, write UNNORMALIZED partials (fp32), q<NF only ----
    long ob = ((long)(half * NB + b) * NH + h) * ((long)QPAD * 64);
    long lb = ((long)(half * NB + b) * NH + h) * QPAD;
#pragma unroll
    for (int u = 0; u < 2; ++u) {
        float l2 = ls[u];
        l2 += __shfl_xor(l2, 16);
        l2 += __shfl_xor(l2, 32);
        int q = qbase + 16 * u + cl;
        if (q < NF) {
            if (quad == 0) lsp[lb + q] = l2;
            float* pr = Opr + ob + (long)q * 64;
            float* pi2 = Opi + ob + (long)q * 64;
#pragma unroll
            for (int nt = 0; nt < 4; ++nt) {
                int d0 = 16 * nt + quad * 4;
                *(f32x4*)(pr + d0) = Or2[nt][u];
                *(f32x4*)(pi2 + d0) = Oi2[nt][u];
            }
        }
    }
}

// ---------------- combine the two key-halves: O = (O1+O2)/(l1+l2), bf16 out ----
__global__ __launch_bounds__(256) void ocombine(
    const float* __restrict__ Opr, const float* __restrict__ Opi,
    const float* __restrict__ lsp, short* __restrict__ Orb, short* __restrict__ Oib) {
    int h = blockIdx.y, b = blockIdx.z;
    int tid = threadIdx.x;
    int q = blockIdx.x * 64 + (tid >> 2);
    int d0 = (tid & 3) * 16;
    if (q >= NF) return;
    long o0 = (((long)b * NH + h) * QPAD + q) * 64 + d0;
    long o1 = ((((long)NB + b) * NH + h) * QPAD + q) * 64 + d0;
    float l = lsp[((long)b * NH + h) * QPAD + q]
            + lsp[(((long)NB + b) * NH + h) * QPAD + q];
    float inv = 1.0f / l;
    long base = (long)b * NF * NE + h * ND;
    short* po = Orb + base + (long)q * NE + d0;
    short* pi = Oib + base + (long)q * NE + d0;
#pragma unroll
    for (int part = 0; part < 2; ++part) {   // 8 d per part
        bf16x8 vr, vi;
#pragma unroll
        for (int sub = 0; sub < 2; ++sub) {
            float4 r1 = *(const float4*)(Opr + o0 + part * 8 + sub * 4);
            float4 r2 = *(const float4*)(Opr + o1 + part * 8 + sub * 4);
            float4 i1 = *(const float4*)(Opi + o0 + part * 8 + sub * 4);
            float4 i2 = *(const float4*)(Opi + o1 + part * 8 + sub * 4);
            vr[sub * 4 + 0] = cvt_bf16((r1.x + r2.x) * inv);
            vr[sub * 4 + 1] = cvt_bf16((r1.y + r2.y) * inv);
            vr[sub * 4 + 2] = cvt_bf16((r1.z + r2.z) * inv);
            vr[sub * 4 + 3] = cvt_bf16((r1.w + r2.w) * inv);
            vi[sub * 4 + 0] = cvt_bf16((i1.x + i2.x) * inv);
            vi[sub * 4 + 1] = cvt_bf16((i1.y + i2.y) * inv);
            vi[sub * 4 + 2] = cvt_bf16((i1.z + i2.z) * inv);
            vi[sub * 4 + 3] = cvt_bf16((i1.w + i2.w) * inv);
        }
        *(bf16x8*)(po + part * 8) = vr;
        *(bf16x8*)(pi + part * 8) = vi;
    }
}

extern "C" void kernel_launch(void* const* d_in, const int* in_sizes, int n_in,
                              void* d_out, int out_size, void* d_ws, size_t ws_size,
                              hipStream_t stream) {
    const float* x   = (const float*)d_in[0];
    const float* g   = (const float*)d_in[1];
    const float* be  = (const float*)d_in[2];
    const float* Wqr = (const float*)d_in[3];
    const float* bqr = (const float*)d_in[4];
    const float* Wqi = (const float*)d_in[5];
    const float* bqi = (const float*)d_in[6];
    const float* Wkr = (const float*)d_in[7];
    const float* bkr = (const float*)d_in[8];
    const float* Wki = (const float*)d_in[9];
    const float* bki = (const float*)d_in[10];
    const float* Wvr = (const float*)d_in[11];
    const float* bvr = (const float*)d_in[12];
    const float* Wvi = (const float*)d_in[13];
    const float* bvi = (const float*)d_in[14];
    const float* Wo  = (const float*)d_in[15];
    float* out = (float*)d_out;

    const long SZ_T = (long)NB * NL * NE;  // 8,388,608
    const long SZ_F = (long)NB * NF * NE;  // 4,196,352
    float2* twg = (float2*)d_ws;            // 2048 float2
    short* xnb = (short*)(twg + 2048);      // bf16 region
    short* xr  = xnb + SZ_T;
    short* xi  = xr + SZ_F;
    short* Qr  = xi + SZ_F;
    short* Qi  = Qr + SZ_F;
    short* Kr  = Qi + SZ_F;
    short* Ki  = Kr + SZ_F;
    short* Vr  = Ki + SZ_F;
    short* Vi  = Vr + SZ_F;
    short* Orb = Vi + SZ_F;
    short* Oib = Orb + SZ_F;
    short* yt  = Oib + SZ_F;                // SZ_T bf16
    short* wb  = yt + SZ_T;                 // 7 * WSZ bf16
    float* Opr = (float*)(wb + 7L * WSZ);   // 2 halves x NB x NH x QPAD x 64 f32
    float* Opi = Opr + 2 * OPSZ;
    float* lsp = Opi + 2 * OPSZ;            // 2 x NB x NH x QPAD f32

    twiddle_kernel<<<NL / 2 / 256, 256, 0, stream>>>(twg);
    castw_kernel<<<dim3(WSZ / 1024, 7), 256, 0, stream>>>(Wqr, Wqi, Wkr, Wki, Wvr, Wvi, Wo, wb);
    ln_kernel<<<NB * NL / 4, 256, 0, stream>>>(x, g, be, xnb);
    rfft_pair<<<NB * 256, 256, 0, stream>>>(xnb, twg, xr, xi);
    int Nf = NB * NF;                       // 8196
    dim3 gq(NE / 128, (Nf + 127) / 128, 3);
    gemm_qkv<<<gq, 256, 0, stream>>>(xr, wb + 0L * WSZ, wb + 2L * WSZ, wb + 4L * WSZ,
                                     bqr, bkr, bvr, Qr, Kr, Vr, Nf);
    gemm_qkv<<<gq, 256, 0, stream>>>(xi, wb + 1L * WSZ, wb + 3L * WSZ, wb + 5L * WSZ,
                                     bqi, bki, bvi, Qi, Ki, Vi, Nf);
    fattn_mfma<<<dim3(17, NH, NB * 2), 256, 0, stream>>>(Qr, Qi, Kr, Ki, Vr, Vi, Opr, Opi, lsp);
    ocombine<<<dim3(33, NH, NB), 256, 0, stream>>>(Opr, Opi, lsp, Orb, Oib);
    irfft_pair<<<NB * 256, 256, 0, stream>>>(Orb, Oib, twg, yt);
    gemm_out<<<dim3(NE / 128, NB * NL / 128), 256, 0, stream>>>(yt, wb + 6L * WSZ, out, NB * NL);
}

// Round 6
// 447.199 us; speedup vs baseline: 1.9144x; 1.9144x over previous
//
#include <hip/hip_runtime.h>
#include <math.h>

#define NB 4
#define NL 4096
#define NE 512
#define NH 8
#define ND 64
#define NF 2049      // NL/2 + 1
#define WSZ (NE * NE) // 262144 elements per weight matrix
#define QPAD 2176    // q rows padded to 17*128 (grid extent!)
#define OPSZ ((long)NB * NH * QPAD * 64)   // one half-partial component

static constexpr float INV_SQRT_N = 1.0f / 64.0f;   // 1/sqrt(4096), ortho norm

typedef __attribute__((ext_vector_type(8))) short bf16x8;
typedef __attribute__((ext_vector_type(4))) short short4v;
typedef __attribute__((ext_vector_type(4))) float f32x4;

__device__ __forceinline__ float2 cmul(float2 a, float2 b) {
    return make_float2(a.x * b.x - a.y * b.y, a.x * b.y + a.y * b.x);
}

__device__ __forceinline__ short cvt_bf16(float f) {
    unsigned u = __float_as_uint(f);
    unsigned r = (u + 0x7FFFu + ((u >> 16) & 1u)) >> 16;
    return (short)r;
}

__device__ __forceinline__ int pack_bf16x2(float a, float b) {
    return (int)(unsigned short)cvt_bf16(a) | ((int)(unsigned short)cvt_bf16(b) << 16);
}

__device__ __forceinline__ float2 unpk(int v) {
    return make_float2(__uint_as_float(((unsigned)v & 0xffffu) << 16),
                       __uint_as_float((unsigned)v & 0xffff0000u));
}

// base-4 digit reversal of a 12-bit index
__device__ __forceinline__ int b4rev(int t) {
    int r = __brev((unsigned)t) >> 20;
    return ((r & 0x555) << 1) | ((r & 0xAAA) >> 1);
}

// ---------------- one-time exact twiddles ----------------
__global__ __launch_bounds__(256) void twiddle_kernel(float2* __restrict__ twg) {
    int j = blockIdx.x * 256 + threadIdx.x;
    double ang = (2.0 * M_PI / (double)NL) * (double)j;
    double s, c;
    sincos(ang, &s, &c);
    twg[j] = make_float2((float)c, (float)s);
}

// ---------------- one-time weight cast fp32 -> bf16 (7 matrices) ----------------
__global__ __launch_bounds__(256) void castw_kernel(
    const float* __restrict__ w0, const float* __restrict__ w1,
    const float* __restrict__ w2, const float* __restrict__ w3,
    const float* __restrict__ w4, const float* __restrict__ w5,
    const float* __restrict__ w6, short* __restrict__ dst) {
    int which = blockIdx.y;
    const float* s = which == 0 ? w0 : which == 1 ? w1 : which == 2 ? w2 :
                     which == 3 ? w3 : which == 4 ? w4 : which == 5 ? w5 : w6;
    long i = (long)blockIdx.x * 1024 + threadIdx.x * 4;
    float4 v = *(const float4*)(s + i);
    short4v o = {cvt_bf16(v.x), cvt_bf16(v.y), cvt_bf16(v.z), cvt_bf16(v.w)};
    *(short4v*)(dst + (long)which * WSZ + i) = o;
}

// ---------------- LayerNorm: one row (512) per wave, bf16 output ----------------
__global__ __launch_bounds__(256) void ln_kernel(
    const float* __restrict__ x, const float* __restrict__ g,
    const float* __restrict__ be, short* __restrict__ xnb) {
    int wv = threadIdx.x >> 6, lane = threadIdx.x & 63;
    long row = (long)blockIdx.x * 4 + wv;
    const float* xp = x + row * NE + lane * 8;
    float4 a = *(const float4*)xp;
    float4 b = *(const float4*)(xp + 4);
    float s  = a.x + a.y + a.z + a.w + b.x + b.y + b.z + b.w;
    float ss = a.x * a.x + a.y * a.y + a.z * a.z + a.w * a.w
             + b.x * b.x + b.y * b.y + b.z * b.z + b.w * b.w;
#pragma unroll
    for (int o = 32; o; o >>= 1) { s += __shfl_xor(s, o); ss += __shfl_xor(ss, o); }
    float mu = s * (1.0f / NE);
    float var = ss * (1.0f / NE) - mu * mu;
    float rs = rsqrtf(var + 1e-5f);
    const float* gp = g + lane * 8;
    const float* bp = be + lane * 8;
    float4 g0 = *(const float4*)gp, g1 = *(const float4*)(gp + 4);
    float4 b0 = *(const float4*)bp, b1 = *(const float4*)(bp + 4);
    bf16x8 ov;
    ov[0] = cvt_bf16((a.x - mu) * rs * g0.x + b0.x);
    ov[1] = cvt_bf16((a.y - mu) * rs * g0.y + b0.y);
    ov[2] = cvt_bf16((a.z - mu) * rs * g0.z + b0.z);
    ov[3] = cvt_bf16((a.w - mu) * rs * g0.w + b0.w);
    ov[4] = cvt_bf16((b.x - mu) * rs * g1.x + b1.x);
    ov[5] = cvt_bf16((b.y - mu) * rs * g1.y + b1.y);
    ov[6] = cvt_bf16((b.z - mu) * rs * g1.z + b1.z);
    ov[7] = cvt_bf16((b.w - mu) * rs * g1.w + b1.w);
    *(bf16x8*)(xnb + row * NE + lane * 8) = ov;
}

// ---------------- radix-4 FFT stages in LDS (4096 pts, 6 stages) ----------------
template <int INV>
__device__ __forceinline__ void fft4_stages(float2* sdata, const float2* tws, int tid) {
#pragma unroll
    for (int st = 0; st < 6; ++st) {
        __syncthreads();
        int Q = 1 << (2 * st);
        int tq = 10 - 2 * st;
#pragma unroll
        for (int jj = 0; jj < 4; ++jj) {
            int j = tid + jj * 256;
            int k = j & (Q - 1);
            int i0 = ((j >> (2 * st)) << (2 * st + 2)) | k;
            float2 w1 = tws[k << tq];
            float2 w2 = tws[(2 * k) << tq];
            float2 w3 = cmul(w1, w2);
            float2 a = sdata[i0];
            float2 b = cmul(w1, sdata[i0 + Q]);
            float2 c = cmul(w2, sdata[i0 + 2 * Q]);
            float2 d = cmul(w3, sdata[i0 + 3 * Q]);
            float2 t0 = make_float2(a.x + c.x, a.y + c.y);
            float2 t1 = make_float2(a.x - c.x, a.y - c.y);
            float2 t2 = make_float2(b.x + d.x, b.y + d.y);
            float2 bd = make_float2(b.x - d.x, b.y - d.y);
            float2 t3 = INV ? make_float2(-bd.y, bd.x) : make_float2(bd.y, -bd.x);
            sdata[i0]         = make_float2(t0.x + t2.x, t0.y + t2.y);
            sdata[i0 + Q]     = make_float2(t1.x + t3.x, t1.y + t3.y);
            sdata[i0 + 2 * Q] = make_float2(t0.x - t2.x, t0.y - t2.y);
            sdata[i0 + 3 * Q] = make_float2(t1.x - t3.x, t1.y - t3.y);
        }
    }
    __syncthreads();
}

// XCD-aware e-pair swizzle: consecutive dispatch ids (round-robin over 8 XCDs)
// map to e-stripes 32 pairs apart, so each XCD owns a contiguous 64-column band.
__device__ __forceinline__ int ep_swizzle(int loc) {
    return ((loc & 7) << 5) | (loc >> 3);
}

// ---------------- forward rfft: 2 real bf16 columns in 1 complex FFT ----------------
__global__ __launch_bounds__(256) void rfft_pair(
    const short* __restrict__ xnb, const float2* __restrict__ twg,
    short* __restrict__ xr, short* __restrict__ xi) {
    __shared__ float2 sdata[NL];
    __shared__ float2 tws[NL / 2];
    int b = blockIdx.x >> 8;
    int e0 = ep_swizzle(blockIdx.x & 255) * 2;
    int tid = threadIdx.x;
    const short* xp = xnb + (long)b * NL * NE + e0;
#pragma unroll
    for (int jj = 0; jj < 16; ++jj) {
        int t = tid + jj * 256;
        int v = *(const int*)(xp + (long)t * NE);
        sdata[b4rev(t)] = unpk(v);
    }
#pragma unroll
    for (int jj = 0; jj < 8; ++jj) {
        int j = tid + jj * 256;
        float2 w = twg[j];
        tws[j] = make_float2(w.x, -w.y);   // forward: e^{-i theta}
    }
    fft4_stages<0>(sdata, tws, tid);
    short* xrp = xr + (long)b * NF * NE + e0;
    short* xip = xi + (long)b * NF * NE + e0;
    for (int f = tid; f < NF; f += 256) {
        int M = (NL - f) & (NL - 1);
        float2 zf = sdata[f], zm = sdata[M];
        float re0 = (zf.x + zm.x) * (0.5f * INV_SQRT_N);
        float im0 = (zf.y - zm.y) * (0.5f * INV_SQRT_N);
        float re1 = (zf.y + zm.y) * (0.5f * INV_SQRT_N);
        float im1 = (zm.x - zf.x) * (0.5f * INV_SQRT_N);
        *(int*)(xrp + (long)f * NE) = pack_bf16x2(re0, re1);
        *(int*)(xip + (long)f * NE) = pack_bf16x2(im0, im1);
    }
}

// ---------------- inverse rfft: bf16 in, bf16 out ----------------
__global__ __launch_bounds__(256) void irfft_pair(
    const short* __restrict__ orr, const short* __restrict__ oii,
    const float2* __restrict__ twg, short* __restrict__ yt) {
    __shared__ float2 sdata[NL];
    __shared__ float2 tws[NL / 2];
    int b = blockIdx.x >> 8;
    int e0 = ep_swizzle(blockIdx.x & 255) * 2;
    int tid = threadIdx.x;
    const short* orp = orr + (long)b * NF * NE + e0;
    const short* oip = oii + (long)b * NF * NE + e0;
    for (int f = tid; f < NF; f += 256) {
        float2 vr = unpk(*(const int*)(orp + (long)f * NE));  // (O0r, O1r)
        float2 vi = unpk(*(const int*)(oip + (long)f * NE));  // (O0i, O1i)
        if (f == 0 || f == NL / 2) vi = make_float2(0.f, 0.f);  // C2R ignores these
        sdata[b4rev(f)] = make_float2(vr.x - vi.y, vi.x + vr.y);
        if (f > 0 && f < NL / 2) {
            sdata[b4rev(NL - f)] = make_float2(vr.x + vi.y, vr.y - vi.x);
        }
    }
#pragma unroll
    for (int jj = 0; jj < 8; ++jj) {
        int j = tid + jj * 256;
        tws[j] = twg[j];                   // inverse: e^{+i theta}
    }
    fft4_stages<1>(sdata, tws, tid);
    short* yp = yt + (long)b * NL * NE + e0;
#pragma unroll
    for (int jj = 0; jj < 16; ++jj) {
        int t = tid + jj * 256;
        float2 z = sdata[t];
        *(int*)(yp + (long)t * NE) = pack_bf16x2(z.x * INV_SQRT_N, z.y * INV_SQRT_N);
    }
}

// ---------------- bf16 MFMA GEMM core ----------------
__device__ __forceinline__ void gemm_core(
    const short* __restrict__ A, const short* __restrict__ W,
    const float* __restrict__ bias, float scale, short* __restrict__ Cb,
    float* __restrict__ Cf, int N) {
    __shared__ short As[128][40];
    __shared__ short Bs[128][40];
    int o0 = blockIdx.x * 128;
    int n0 = blockIdx.y * 128;
    int tid = threadIdx.x;
    int lane = tid & 63, wv = tid >> 6;
    int quad = lane >> 4, cl = lane & 15;
    int rbase = (wv >> 1) << 6;
    int cbase = (wv & 1) << 6;
    int srow = tid >> 2;    // 0..63
    int sseg = tid & 3;     // 0..3
    f32x4 acc[4][4];
#pragma unroll
    for (int i = 0; i < 4; ++i)
#pragma unroll
        for (int j = 0; j < 4; ++j) acc[i][j] = (f32x4){0, 0, 0, 0};

    int ra = n0 + srow;      if (ra >= N) ra = N - 1;
    int rb = n0 + srow + 64; if (rb >= N) rb = N - 1;
    const short* Ap0 = A + (long)ra * NE + sseg * 8;
    const short* Ap1 = A + (long)rb * NE + sseg * 8;
    const short* Wp0 = W + (long)(o0 + srow) * NE + sseg * 8;
    const short* Wp1 = W + (long)(o0 + srow + 64) * NE + sseg * 8;

    bf16x8 a0 = *(const bf16x8*)Ap0, a1 = *(const bf16x8*)Ap1;
    bf16x8 b0 = *(const bf16x8*)Wp0, b1 = *(const bf16x8*)Wp1;

    for (int kt = 0; kt < 16; ++kt) {
        __syncthreads();
        *(bf16x8*)&As[srow][sseg * 8] = a0;
        *(bf16x8*)&As[srow + 64][sseg * 8] = a1;
        *(bf16x8*)&Bs[srow][sseg * 8] = b0;
        *(bf16x8*)&Bs[srow + 64][sseg * 8] = b1;
        __syncthreads();
        if (kt < 15) {
            int ko = (kt + 1) * 32;
            a0 = *(const bf16x8*)(Ap0 + ko);
            a1 = *(const bf16x8*)(Ap1 + ko);
            b0 = *(const bf16x8*)(Wp0 + ko);
            b1 = *(const bf16x8*)(Wp1 + ko);
        }
        bf16x8 ar[4], br[4];
#pragma unroll
        for (int i = 0; i < 4; ++i) ar[i] = *(const bf16x8*)&As[rbase + 16 * i + cl][quad * 8];
#pragma unroll
        for (int j = 0; j < 4; ++j) br[j] = *(const bf16x8*)&Bs[cbase + 16 * j + cl][quad * 8];
#pragma unroll
        for (int i = 0; i < 4; ++i)
#pragma unroll
            for (int j = 0; j < 4; ++j)
                acc[i][j] = __builtin_amdgcn_mfma_f32_16x16x32_bf16(ar[i], br[j], acc[i][j], 0, 0, 0);
    }
    float bv[4];
#pragma unroll
    for (int j = 0; j < 4; ++j) bv[j] = bias ? bias[o0 + cbase + 16 * j + cl] : 0.0f;
#pragma unroll
    for (int i = 0; i < 4; ++i) {
#pragma unroll
        for (int r = 0; r < 4; ++r) {
            int n = n0 + rbase + 16 * i + quad * 4 + r;
            if (n >= N) continue;
#pragma unroll
            for (int j = 0; j < 4; ++j) {
                float v = (acc[i][j][r] + bv[j]) * scale;
                int o = o0 + cbase + 16 * j + cl;
                if (Cb) Cb[(long)n * NE + o] = cvt_bf16(v);
                else    Cf[(long)n * NE + o] = v;
            }
        }
    }
}

__global__ __launch_bounds__(256) void gemm_qkv(
    const short* __restrict__ A,
    const short* __restrict__ W0, const short* __restrict__ W1, const short* __restrict__ W2,
    const float* __restrict__ b0, const float* __restrict__ b1, const float* __restrict__ b2,
    short* __restrict__ C0, short* __restrict__ C1, short* __restrict__ C2, int N) {
    int z = blockIdx.z;
    const short* W = z == 0 ? W0 : z == 1 ? W1 : W2;
    const float* bb = z == 0 ? b0 : z == 1 ? b1 : b2;
    short* C = z == 0 ? C0 : z == 1 ? C1 : C2;
    gemm_core(A, W, bb, z == 0 ? 0.125f : 1.0f, C, nullptr, N);
}

__global__ __launch_bounds__(256) void gemm_out(
    const short* __restrict__ A, const short* __restrict__ W,
    float* __restrict__ C, int N) {
    gemm_core(A, W, nullptr, 1.0f, nullptr, C, N);
}

// ---------------- MFMA flash attention: register-resident P (S^T trick) ----------------
// S^T = K.Q^T via mfma_16x16x32 (C rows = key, cols = q). Its C-layout IS the
// B-operand layout of mfma_16x16x16bf16_1k, so P never touches LDS:
// O^T = V^T.P^T accumulated per 16-d tile. l is per-lane (q=lane&15).
// Vt swizzled at 4-short granularity: col-group g' = g ^ ((d>>2)&15).
// R1: 128 q-rows per block (2 q-subtiles u=0,1 per wave).
// R3: KEY-SPLIT (flash-decoding): blockIdx.z = b*2+half; each block does half
// the K/V tiles (17 or 16), writes UNNORMALIZED fp32 partial O + partial l.
// R4: QPAD=2176 (grid q-extent) + q<NF guard on partial writes.
// R5: NO min-waves clamp in launch_bounds — (256,4) forced VGPR=64 and the
// ~120-live-reg kernel spilled 2.1 GB to scratch (fattn 545us, MfmaUtil 8%).
__global__ __launch_bounds__(256) void fattn_mfma(
    const short* __restrict__ Qr, const short* __restrict__ Qi,
    const short* __restrict__ Kr, const short* __restrict__ Ki,
    const short* __restrict__ Vr, const short* __restrict__ Vi,
    float* __restrict__ Opr, float* __restrict__ Opi, float* __restrict__ lsp) {
    __shared__ short Ks[2][64][72];   // [r/i][key][d]
    __shared__ short Vt[2][64][72];   // [r/i][d][key 4-swizzled]
    int tid = threadIdx.x;
    int wv = tid >> 6, lane = tid & 63;
    int quad = lane >> 4, cl = lane & 15;
    int h = blockIdx.y;
    int zz = blockIdx.z;
    int b = zz >> 1, half = zz & 1;
    long base = (long)b * NF * NE + h * ND;
    int qbase = blockIdx.x * 128 + wv * 32;
    int kt0 = half * 17;
    int ktN = half ? 33 : 17;

    int sk0 = (tid >> 4) << 2;   // staged keys (group g0 = tid>>4)
    int sd0 = (tid & 15) << 2;   // staged dims
    int g0 = tid >> 4;
    int dsw = tid & 15;          // (d>>2) for all 4 staged dim rows

    // ---- Q fragments: B-operand of S^T (B[k=d][n=q]), pre-scaled by 1/8 ----
    bf16x8 qar[2][2], qai[2][2];
#pragma unroll
    for (int u = 0; u < 2; ++u) {
        int qrow = qbase + 16 * u + cl; if (qrow >= NF) qrow = NF - 1;
        const short* pr = Qr + base + (long)qrow * NE + 8 * quad;
        const short* pi = Qi + base + (long)qrow * NE + 8 * quad;
        qar[u][0] = *(const bf16x8*)pr;
        qar[u][1] = *(const bf16x8*)(pr + 32);
        qai[u][0] = *(const bf16x8*)pi;
        qai[u][1] = *(const bf16x8*)(pi + 32);
    }

    float ls[2] = {0.f, 0.f};
    f32x4 Or2[4][2], Oi2[4][2];   // O^T tiles: rows d=16nt+quad*4+r, col q=16u+cl
#pragma unroll
    for (int t = 0; t < 4; ++t)
#pragma unroll
        for (int u = 0; u < 2; ++u) {
            Or2[t][u] = (f32x4){0, 0, 0, 0};
            Oi2[t][u] = (f32x4){0, 0, 0, 0};
        }

    short4v lk0[4], lk1[4], lv0[4], lv1[4];
    const long TSTEP = (long)64 * NE;
    const short* pKr = Kr + base + (long)sk0 * NE + sd0 + (long)kt0 * TSTEP;
    const short* pKi = Ki + base + (long)sk0 * NE + sd0 + (long)kt0 * TSTEP;
    const short* pVr = Vr + base + (long)sk0 * NE + sd0 + (long)kt0 * TSTEP;
    const short* pVi = Vi + base + (long)sk0 * NE + sd0 + (long)kt0 * TSTEP;

    auto ldfull = [&]() {
#pragma unroll
        for (int kk = 0; kk < 4; ++kk) {
            long o = (long)kk * NE;
            lk0[kk] = *(const short4v*)(pKr + o);
            lk1[kk] = *(const short4v*)(pKi + o);
            lv0[kk] = *(const short4v*)(pVr + o);
            lv1[kk] = *(const short4v*)(pVi + o);
        }
        pKr += TSTEP; pKi += TSTEP; pVr += TSTEP; pVi += TSTEP;
    };
    auto ldmask = [&]() {   // tile 32: keys 2048..2111, mask >= NF
        short4v z4 = {0, 0, 0, 0};
#pragma unroll
        for (int kk = 0; kk < 4; ++kk) {
            int mg = 2048 + sk0 + kk;
            if (mg < NF) {
                long o = (long)kk * NE;
                lk0[kk] = *(const short4v*)(pKr + o);
                lk1[kk] = *(const short4v*)(pKi + o);
                lv0[kk] = *(const short4v*)(pVr + o);
                lv1[kk] = *(const short4v*)(pVi + o);
            } else { lk0[kk] = z4; lk1[kk] = z4; lv0[kk] = z4; lv1[kk] = z4; }
        }
    };
    ldfull();   // regs <- tile kt0

    for (int kt = kt0; kt < ktN; ++kt) {
        __syncthreads();
        // ---- stage K (row-major) + V (transposed, 4-granular XOR swizzle) ----
#pragma unroll
        for (int kk = 0; kk < 4; ++kk) {
            *(short4v*)&Ks[0][sk0 + kk][sd0] = lk0[kk];
            *(short4v*)&Ks[1][sk0 + kk][sd0] = lk1[kk];
        }
        {
            int cv = (g0 ^ dsw) << 2;
#pragma unroll
            for (int dd = 0; dd < 4; ++dd) {
                short4v t0 = {lv0[0][dd], lv0[1][dd], lv0[2][dd], lv0[3][dd]};
                *(short4v*)&Vt[0][sd0 + dd][cv] = t0;
                short4v t1 = {lv1[0][dd], lv1[1][dd], lv1[2][dd], lv1[3][dd]};
                *(short4v*)&Vt[1][sd0 + dd][cv] = t1;
            }
        }
        __syncthreads();
        if (kt + 1 < ktN) {                 // prefetch next tile into regs
            if (kt + 1 < 32) ldfull();
            else ldmask();
        }

        // ---- S^T = K.Q^T (32 MFMAs): c[t][u] rows = key quad*4+r, col = q ----
        f32x4 c[4][2];
        __builtin_amdgcn_s_setprio(1);
#pragma unroll
        for (int t = 0; t < 4; ++t) {
            const short* kr = &Ks[0][cl + 16 * t][8 * quad];
            const short* ki = &Ks[1][cl + 16 * t][8 * quad];
            bf16x8 k0 = *(const bf16x8*)kr;
            bf16x8 k1 = *(const bf16x8*)(kr + 32);
            bf16x8 k2 = *(const bf16x8*)ki;
            bf16x8 k3 = *(const bf16x8*)(ki + 32);
#pragma unroll
            for (int u = 0; u < 2; ++u) {
                f32x4 acc = (f32x4){0, 0, 0, 0};
                acc = __builtin_amdgcn_mfma_f32_16x16x32_bf16(k0, qar[u][0], acc, 0, 0, 0);
                acc = __builtin_amdgcn_mfma_f32_16x16x32_bf16(k1, qar[u][1], acc, 0, 0, 0);
                acc = __builtin_amdgcn_mfma_f32_16x16x32_bf16(k2, qai[u][0], acc, 0, 0, 0);
                acc = __builtin_amdgcn_mfma_f32_16x16x32_bf16(k3, qai[u][1], acc, 0, 0, 0);
                c[t][u] = acc;
            }
        }
        __builtin_amdgcn_s_setprio(0);

        // ---- exp (no max-sub: |s|<~5), per-lane l, pack B-operands ----
        short4v pb[4][2];
        if (kt < 32) {   // all 64 keys valid: branch-free
#pragma unroll
            for (int t = 0; t < 4; ++t)
#pragma unroll
                for (int u = 0; u < 2; ++u) {
                    float p0 = __expf(c[t][u][0]);
                    float p1 = __expf(c[t][u][1]);
                    float p2 = __expf(c[t][u][2]);
                    float p3 = __expf(c[t][u][3]);
                    ls[u] += (p0 + p1) + (p2 + p3);
                    pb[t][u] = (short4v){cvt_bf16(p0), cvt_bf16(p1),
                                         cvt_bf16(p2), cvt_bf16(p3)};
                }
        } else {         // tail tile: mask keys >= NF
#pragma unroll
            for (int t = 0; t < 4; ++t) {
                int kbase = 2048 + 16 * t + quad * 4;
#pragma unroll
                for (int u = 0; u < 2; ++u) {
                    float p0 = (kbase + 0 < NF) ? __expf(c[t][u][0]) : 0.0f;
                    float p1 = (kbase + 1 < NF) ? __expf(c[t][u][1]) : 0.0f;
                    float p2 = (kbase + 2 < NF) ? __expf(c[t][u][2]) : 0.0f;
                    float p3 = (kbase + 3 < NF) ? __expf(c[t][u][3]) : 0.0f;
                    ls[u] += (p0 + p1) + (p2 + p3);
                    pb[t][u] = (short4v){cvt_bf16(p0), cvt_bf16(p1),
                                         cvt_bf16(p2), cvt_bf16(p3)};
                }
            }
        }

        // ---- O^T += V^T.P^T  (64 mfma_16x16x16, P in registers) ----
        __builtin_amdgcn_s_setprio(1);
#pragma unroll
        for (int nt = 0; nt < 4; ++nt) {
            int d = cl + 16 * nt;
            int dg = (d >> 2) & 15;
#pragma unroll
            for (int t = 0; t < 4; ++t) {
                int g = 4 * t + quad;
                int cv = ((g ^ dg) << 2);
                short4v va = *(const short4v*)&Vt[0][d][cv];
                short4v vb = *(const short4v*)&Vt[1][d][cv];
#pragma unroll
                for (int u = 0; u < 2; ++u) {
                    Or2[nt][u] = __builtin_amdgcn_mfma_f32_16x16x16bf16_1k(va, pb[t][u], Or2[nt][u], 0, 0, 0);
                    Oi2[nt][u] = __builtin_amdgcn_mfma_f32_16x16x16bf16_1k(vb, pb[t][u], Oi2[nt][u], 0, 0, 0);
                }
            }
        }
        __builtin_amdgcn_s_setprio(0);
    }

    // ---- l reduce over quads, write UNNORMALIZED partials (fp32), q<NF only ----
    long ob = ((long)(half * NB + b) * NH + h) * ((long)QPAD * 64);
    long lb = ((long)(half * NB + b) * NH + h) * QPAD;
#pragma unroll
    for (int u = 0; u < 2; ++u) {
        float l2 = ls[u];
        l2 += __shfl_xor(l2, 16);
        l2 += __shfl_xor(l2, 32);
        int q = qbase + 16 * u + cl;
        if (q < NF) {
            if (quad == 0) lsp[lb + q] = l2;
            float* pr = Opr + ob + (long)q * 64;
            float* pi2 = Opi + ob + (long)q * 64;
#pragma unroll
            for (int nt = 0; nt < 4; ++nt) {
                int d0 = 16 * nt + quad * 4;
                *(f32x4*)(pr + d0) = Or2[nt][u];
                *(f32x4*)(pi2 + d0) = Oi2[nt][u];
            }
        }
    }
}

// ---------------- combine the two key-halves: O = (O1+O2)/(l1+l2), bf16 out ----
__global__ __launch_bounds__(256) void ocombine(
    const float* __restrict__ Opr, const float* __restrict__ Opi,
    const float* __restrict__ lsp, short* __restrict__ Orb, short* __restrict__ Oib) {
    int h = blockIdx.y, b = blockIdx.z;
    int tid = threadIdx.x;
    int q = blockIdx.x * 64 + (tid >> 2);
    int d0 = (tid & 3) * 16;
    if (q >= NF) return;
    long o0 = (((long)b * NH + h) * QPAD + q) * 64 + d0;
    long o1 = ((((long)NB + b) * NH + h) * QPAD + q) * 64 + d0;
    float l = lsp[((long)b * NH + h) * QPAD + q]
            + lsp[(((long)NB + b) * NH + h) * QPAD + q];
    float inv = 1.0f / l;
    long base = (long)b * NF * NE + h * ND;
    short* po = Orb + base + (long)q * NE + d0;
    short* pi = Oib + base + (long)q * NE + d0;
#pragma unroll
    for (int part = 0; part < 2; ++part) {   // 8 d per part
        bf16x8 vr, vi;
#pragma unroll
        for (int sub = 0; sub < 2; ++sub) {
            float4 r1 = *(const float4*)(Opr + o0 + part * 8 + sub * 4);
            float4 r2 = *(const float4*)(Opr + o1 + part * 8 + sub * 4);
            float4 i1 = *(const float4*)(Opi + o0 + part * 8 + sub * 4);
            float4 i2 = *(const float4*)(Opi + o1 + part * 8 + sub * 4);
            vr[sub * 4 + 0] = cvt_bf16((r1.x + r2.x) * inv);
            vr[sub * 4 + 1] = cvt_bf16((r1.y + r2.y) * inv);
            vr[sub * 4 + 2] = cvt_bf16((r1.z + r2.z) * inv);
            vr[sub * 4 + 3] = cvt_bf16((r1.w + r2.w) * inv);
            vi[sub * 4 + 0] = cvt_bf16((i1.x + i2.x) * inv);
            vi[sub * 4 + 1] = cvt_bf16((i1.y + i2.y) * inv);
            vi[sub * 4 + 2] = cvt_bf16((i1.z + i2.z) * inv);
            vi[sub * 4 + 3] = cvt_bf16((i1.w + i2.w) * inv);
        }
        *(bf16x8*)(po + part * 8) = vr;
        *(bf16x8*)(pi + part * 8) = vi;
    }
}

extern "C" void kernel_launch(void* const* d_in, const int* in_sizes, int n_in,
                              void* d_out, int out_size, void* d_ws, size_t ws_size,
                              hipStream_t stream) {
    const float* x   = (const float*)d_in[0];
    const float* g   = (const float*)d_in[1];
    const float* be  = (const float*)d_in[2];
    const float* Wqr = (const float*)d_in[3];
    const float* bqr = (const float*)d_in[4];
    const float* Wqi = (const float*)d_in[5];
    const float* bqi = (const float*)d_in[6];
    const float* Wkr = (const float*)d_in[7];
    const float* bkr = (const float*)d_in[8];
    const float* Wki = (const float*)d_in[9];
    const float* bki = (const float*)d_in[10];
    const float* Wvr = (const float*)d_in[11];
    const float* bvr = (const float*)d_in[12];
    const float* Wvi = (const float*)d_in[13];
    const float* bvi = (const float*)d_in[14];
    const float* Wo  = (const float*)d_in[15];
    float* out = (float*)d_out;

    const long SZ_T = (long)NB * NL * NE;  // 8,388,608
    const long SZ_F = (long)NB * NF * NE;  // 4,196,352
    float2* twg = (float2*)d_ws;            // 2048 float2
    short* xnb = (short*)(twg + 2048);      // bf16 region
    short* xr  = xnb + SZ_T;
    short* xi  = xr + SZ_F;
    short* Qr  = xi + SZ_F;
    short* Qi  = Qr + SZ_F;
    short* Kr  = Qi + SZ_F;
    short* Ki  = Kr + SZ_F;
    short* Vr  = Ki + SZ_F;
    short* Vi  = Vr + SZ_F;
    short* Orb = Vi + SZ_F;
    short* Oib = Orb + SZ_F;
    short* yt  = Oib + SZ_F;                // SZ_T bf16
    short* wb  = yt + SZ_T;                 // 7 * WSZ bf16
    float* Opr = (float*)(wb + 7L * WSZ);   // 2 halves x NB x NH x QPAD x 64 f32
    float* Opi = Opr + 2 * OPSZ;
    float* lsp = Opi + 2 * OPSZ;            // 2 x NB x NH x QPAD f32

    twiddle_kernel<<<NL / 2 / 256, 256, 0, stream>>>(twg);
    castw_kernel<<<dim3(WSZ / 1024, 7), 256, 0, stream>>>(Wqr, Wqi, Wkr, Wki, Wvr, Wvi, Wo, wb);
    ln_kernel<<<NB * NL / 4, 256, 0, stream>>>(x, g, be, xnb);
    rfft_pair<<<NB * 256, 256, 0, stream>>>(xnb, twg, xr, xi);
    int Nf = NB * NF;                       // 8196
    dim3 gq(NE / 128, (Nf + 127) / 128, 3);
    gemm_qkv<<<gq, 256, 0, stream>>>(xr, wb + 0L * WSZ, wb + 2L * WSZ, wb + 4L * WSZ,
                                     bqr, bkr, bvr, Qr, Kr, Vr, Nf);
    gemm_qkv<<<gq, 256, 0, stream>>>(xi, wb + 1L * WSZ, wb + 3L * WSZ, wb + 5L * WSZ,
                                     bqi, bki, bvi, Qi, Ki, Vi, Nf);
    fattn_mfma<<<dim3(17, NH, NB * 2), 256, 0, stream>>>(Qr, Qi, Kr, Ki, Vr, Vi, Opr, Opi, lsp);
    ocombine<<<dim3(33, NH, NB), 256, 0, stream>>>(Opr, Opi, lsp, Orb, Oib);
    irfft_pair<<<NB * 256, 256, 0, stream>>>(Orb, Oib, twg, yt);
    gemm_out<<<dim3(NE / 128, NB * NL / 128), 256, 0, stream>>>(yt, wb + 6L * WSZ, out, NB * NL);
}

// Round 7
// 429.662 us; speedup vs baseline: 1.9925x; 1.0408x over previous
//
#include <hip/hip_runtime.h>
#include <math.h>

#define NB 4
#define NL 4096
#define NE 512
#define NH 8
#define ND 64
#define NF 2049      // NL/2 + 1
#define WSZ (NE * NE) // 262144 elements per weight matrix
#define QPAD 2176    // q rows padded to 17*128 (grid extent!)
#define OPSZ ((long)NB * NH * QPAD * 64)   // one half-partial component

static constexpr float INV_SQRT_N = 1.0f / 64.0f;   // 1/sqrt(4096), ortho norm

typedef __attribute__((ext_vector_type(8))) short bf16x8;
typedef __attribute__((ext_vector_type(4))) short short4v;
typedef __attribute__((ext_vector_type(4))) float f32x4;

__device__ __forceinline__ float2 cmul(float2 a, float2 b) {
    return make_float2(a.x * b.x - a.y * b.y, a.x * b.y + a.y * b.x);
}

__device__ __forceinline__ short cvt_bf16(float f) {
    unsigned u = __float_as_uint(f);
    unsigned r = (u + 0x7FFFu + ((u >> 16) & 1u)) >> 16;
    return (short)r;
}

__device__ __forceinline__ int pack_bf16x2(float a, float b) {
    return (int)(unsigned short)cvt_bf16(a) | ((int)(unsigned short)cvt_bf16(b) << 16);
}

// HW packed f32->bf16 (RTNE), 1 inst per pair (T12 primitive, gfx950-verified)
__device__ __forceinline__ short4v pk4(float a, float b, float c, float d) {
    union { unsigned u[2]; short4v s; } r;
    asm("v_cvt_pk_bf16_f32 %0, %1, %2" : "=v"(r.u[0]) : "v"(a), "v"(b));
    asm("v_cvt_pk_bf16_f32 %0, %1, %2" : "=v"(r.u[1]) : "v"(c), "v"(d));
    return r.s;
}

__device__ __forceinline__ float2 unpk(int v) {
    return make_float2(__uint_as_float(((unsigned)v & 0xffffu) << 16),
                       __uint_as_float((unsigned)v & 0xffff0000u));
}

// base-4 digit reversal of a 12-bit index
__device__ __forceinline__ int b4rev(int t) {
    int r = __brev((unsigned)t) >> 20;
    return ((r & 0x555) << 1) | ((r & 0xAAA) >> 1);
}

// ---------------- one-time exact twiddles ----------------
__global__ __launch_bounds__(256) void twiddle_kernel(float2* __restrict__ twg) {
    int j = blockIdx.x * 256 + threadIdx.x;
    double ang = (2.0 * M_PI / (double)NL) * (double)j;
    double s, c;
    sincos(ang, &s, &c);
    twg[j] = make_float2((float)c, (float)s);
}

// ---------------- one-time weight cast fp32 -> bf16 (7 matrices) ----------------
__global__ __launch_bounds__(256) void castw_kernel(
    const float* __restrict__ w0, const float* __restrict__ w1,
    const float* __restrict__ w2, const float* __restrict__ w3,
    const float* __restrict__ w4, const float* __restrict__ w5,
    const float* __restrict__ w6, short* __restrict__ dst) {
    int which = blockIdx.y;
    const float* s = which == 0 ? w0 : which == 1 ? w1 : which == 2 ? w2 :
                     which == 3 ? w3 : which == 4 ? w4 : which == 5 ? w5 : w6;
    long i = (long)blockIdx.x * 1024 + threadIdx.x * 4;
    float4 v = *(const float4*)(s + i);
    short4v o = {cvt_bf16(v.x), cvt_bf16(v.y), cvt_bf16(v.z), cvt_bf16(v.w)};
    *(short4v*)(dst + (long)which * WSZ + i) = o;
}

// ---------------- LayerNorm: one row (512) per wave, bf16 output ----------------
__global__ __launch_bounds__(256) void ln_kernel(
    const float* __restrict__ x, const float* __restrict__ g,
    const float* __restrict__ be, short* __restrict__ xnb) {
    int wv = threadIdx.x >> 6, lane = threadIdx.x & 63;
    long row = (long)blockIdx.x * 4 + wv;
    const float* xp = x + row * NE + lane * 8;
    float4 a = *(const float4*)xp;
    float4 b = *(const float4*)(xp + 4);
    float s  = a.x + a.y + a.z + a.w + b.x + b.y + b.z + b.w;
    float ss = a.x * a.x + a.y * a.y + a.z * a.z + a.w * a.w
             + b.x * b.x + b.y * b.y + b.z * b.z + b.w * b.w;
#pragma unroll
    for (int o = 32; o; o >>= 1) { s += __shfl_xor(s, o); ss += __shfl_xor(ss, o); }
    float mu = s * (1.0f / NE);
    float var = ss * (1.0f / NE) - mu * mu;
    float rs = rsqrtf(var + 1e-5f);
    const float* gp = g + lane * 8;
    const float* bp = be + lane * 8;
    float4 g0 = *(const float4*)gp, g1 = *(const float4*)(gp + 4);
    float4 b0 = *(const float4*)bp, b1 = *(const float4*)(bp + 4);
    bf16x8 ov;
    ov[0] = cvt_bf16((a.x - mu) * rs * g0.x + b0.x);
    ov[1] = cvt_bf16((a.y - mu) * rs * g0.y + b0.y);
    ov[2] = cvt_bf16((a.z - mu) * rs * g0.z + b0.z);
    ov[3] = cvt_bf16((a.w - mu) * rs * g0.w + b0.w);
    ov[4] = cvt_bf16((b.x - mu) * rs * g1.x + b1.x);
    ov[5] = cvt_bf16((b.y - mu) * rs * g1.y + b1.y);
    ov[6] = cvt_bf16((b.z - mu) * rs * g1.z + b1.z);
    ov[7] = cvt_bf16((b.w - mu) * rs * g1.w + b1.w);
    *(bf16x8*)(xnb + row * NE + lane * 8) = ov;
}

// ---------------- radix-4 FFT stages in LDS (4096 pts, 6 stages) ----------------
template <int INV>
__device__ __forceinline__ void fft4_stages(float2* sdata, const float2* tws, int tid) {
#pragma unroll
    for (int st = 0; st < 6; ++st) {
        __syncthreads();
        int Q = 1 << (2 * st);
        int tq = 10 - 2 * st;
#pragma unroll
        for (int jj = 0; jj < 4; ++jj) {
            int j = tid + jj * 256;
            int k = j & (Q - 1);
            int i0 = ((j >> (2 * st)) << (2 * st + 2)) | k;
            float2 w1 = tws[k << tq];
            float2 w2 = tws[(2 * k) << tq];
            float2 w3 = cmul(w1, w2);
            float2 a = sdata[i0];
            float2 b = cmul(w1, sdata[i0 + Q]);
            float2 c = cmul(w2, sdata[i0 + 2 * Q]);
            float2 d = cmul(w3, sdata[i0 + 3 * Q]);
            float2 t0 = make_float2(a.x + c.x, a.y + c.y);
            float2 t1 = make_float2(a.x - c.x, a.y - c.y);
            float2 t2 = make_float2(b.x + d.x, b.y + d.y);
            float2 bd = make_float2(b.x - d.x, b.y - d.y);
            float2 t3 = INV ? make_float2(-bd.y, bd.x) : make_float2(bd.y, -bd.x);
            sdata[i0]         = make_float2(t0.x + t2.x, t0.y + t2.y);
            sdata[i0 + Q]     = make_float2(t1.x + t3.x, t1.y + t3.y);
            sdata[i0 + 2 * Q] = make_float2(t0.x - t2.x, t0.y - t2.y);
            sdata[i0 + 3 * Q] = make_float2(t1.x - t3.x, t1.y - t3.y);
        }
    }
    __syncthreads();
}

// XCD-aware e-pair swizzle: consecutive dispatch ids (round-robin over 8 XCDs)
// map to e-stripes 32 pairs apart, so each XCD owns a contiguous 64-column band.
__device__ __forceinline__ int ep_swizzle(int loc) {
    return ((loc & 7) << 5) | (loc >> 3);
}

// ---------------- forward rfft: 2 real bf16 columns in 1 complex FFT ----------------
__global__ __launch_bounds__(256) void rfft_pair(
    const short* __restrict__ xnb, const float2* __restrict__ twg,
    short* __restrict__ xr, short* __restrict__ xi) {
    __shared__ float2 sdata[NL];
    __shared__ float2 tws[NL / 2];
    int b = blockIdx.x >> 8;
    int e0 = ep_swizzle(blockIdx.x & 255) * 2;
    int tid = threadIdx.x;
    const short* xp = xnb + (long)b * NL * NE + e0;
#pragma unroll
    for (int jj = 0; jj < 16; ++jj) {
        int t = tid + jj * 256;
        int v = *(const int*)(xp + (long)t * NE);
        sdata[b4rev(t)] = unpk(v);
    }
#pragma unroll
    for (int jj = 0; jj < 8; ++jj) {
        int j = tid + jj * 256;
        float2 w = twg[j];
        tws[j] = make_float2(w.x, -w.y);   // forward: e^{-i theta}
    }
    fft4_stages<0>(sdata, tws, tid);
    short* xrp = xr + (long)b * NF * NE + e0;
    short* xip = xi + (long)b * NF * NE + e0;
    for (int f = tid; f < NF; f += 256) {
        int M = (NL - f) & (NL - 1);
        float2 zf = sdata[f], zm = sdata[M];
        float re0 = (zf.x + zm.x) * (0.5f * INV_SQRT_N);
        float im0 = (zf.y - zm.y) * (0.5f * INV_SQRT_N);
        float re1 = (zf.y + zm.y) * (0.5f * INV_SQRT_N);
        float im1 = (zm.x - zf.x) * (0.5f * INV_SQRT_N);
        *(int*)(xrp + (long)f * NE) = pack_bf16x2(re0, re1);
        *(int*)(xip + (long)f * NE) = pack_bf16x2(im0, im1);
    }
}

// ---------------- inverse rfft, FUSED with key-half combine (R6) ----------------
// Reads fp32 unnormalized partials of both key-halves + partial l, combines
// (O1+O2)/(l1+l2) inline during the gather. Same fp32 math as the old
// ocombine kernel — relocated, not changed. Block's e-band = one head, so
// partial rows are L2-shared across the XCD's 32 e-pair blocks.
__global__ __launch_bounds__(256) void irfft_pair(
    const float* __restrict__ Opr, const float* __restrict__ Opi,
    const float* __restrict__ lsp, const float2* __restrict__ twg,
    short* __restrict__ yt) {
    __shared__ float2 sdata[NL];
    __shared__ float2 tws[NL / 2];
    int b = blockIdx.x >> 8;
    int e0 = ep_swizzle(blockIdx.x & 255) * 2;
    int tid = threadIdx.x;
    int h = e0 >> 6, d0 = e0 & 63;
    long p0 = ((long)b * NH + h) * ((long)QPAD * 64) + d0;
    long p1 = ((long)(NB + b) * NH + h) * ((long)QPAD * 64) + d0;
    long l0 = ((long)b * NH + h) * QPAD;
    long l1 = ((long)(NB + b) * NH + h) * QPAD;
    for (int f = tid; f < NF; f += 256) {
        float l = lsp[l0 + f] + lsp[l1 + f];
        float inv = 1.0f / l;
        float2 r1 = *(const float2*)(Opr + p0 + (long)f * 64);
        float2 r2 = *(const float2*)(Opr + p1 + (long)f * 64);
        float2 i1 = *(const float2*)(Opi + p0 + (long)f * 64);
        float2 i2 = *(const float2*)(Opi + p1 + (long)f * 64);
        float2 vr = make_float2((r1.x + r2.x) * inv, (r1.y + r2.y) * inv);
        float2 vi = make_float2((i1.x + i2.x) * inv, (i1.y + i2.y) * inv);
        if (f == 0 || f == NL / 2) vi = make_float2(0.f, 0.f);  // C2R ignores these
        sdata[b4rev(f)] = make_float2(vr.x - vi.y, vi.x + vr.y);
        if (f > 0 && f < NL / 2) {
            sdata[b4rev(NL - f)] = make_float2(vr.x + vi.y, vr.y - vi.x);
        }
    }
#pragma unroll
    for (int jj = 0; jj < 8; ++jj) {
        int j = tid + jj * 256;
        tws[j] = twg[j];                   // inverse: e^{+i theta}
    }
    fft4_stages<1>(sdata, tws, tid);
    short* yp = yt + (long)b * NL * NE + e0;
#pragma unroll
    for (int jj = 0; jj < 16; ++jj) {
        int t = tid + jj * 256;
        float2 z = sdata[t];
        *(int*)(yp + (long)t * NE) = pack_bf16x2(z.x * INV_SQRT_N, z.y * INV_SQRT_N);
    }
}

// ---------------- bf16 MFMA GEMM core ----------------
__device__ __forceinline__ void gemm_core(
    const short* __restrict__ A, const short* __restrict__ W,
    const float* __restrict__ bias, float scale, short* __restrict__ Cb,
    float* __restrict__ Cf, int N) {
    __shared__ short As[128][40];
    __shared__ short Bs[128][40];
    int o0 = blockIdx.x * 128;
    int n0 = blockIdx.y * 128;
    int tid = threadIdx.x;
    int lane = tid & 63, wv = tid >> 6;
    int quad = lane >> 4, cl = lane & 15;
    int rbase = (wv >> 1) << 6;
    int cbase = (wv & 1) << 6;
    int srow = tid >> 2;    // 0..63
    int sseg = tid & 3;     // 0..3
    f32x4 acc[4][4];
#pragma unroll
    for (int i = 0; i < 4; ++i)
#pragma unroll
        for (int j = 0; j < 4; ++j) acc[i][j] = (f32x4){0, 0, 0, 0};

    int ra = n0 + srow;      if (ra >= N) ra = N - 1;
    int rb = n0 + srow + 64; if (rb >= N) rb = N - 1;
    const short* Ap0 = A + (long)ra * NE + sseg * 8;
    const short* Ap1 = A + (long)rb * NE + sseg * 8;
    const short* Wp0 = W + (long)(o0 + srow) * NE + sseg * 8;
    const short* Wp1 = W + (long)(o0 + srow + 64) * NE + sseg * 8;

    bf16x8 a0 = *(const bf16x8*)Ap0, a1 = *(const bf16x8*)Ap1;
    bf16x8 b0 = *(const bf16x8*)Wp0, b1 = *(const bf16x8*)Wp1;

    for (int kt = 0; kt < 16; ++kt) {
        __syncthreads();
        *(bf16x8*)&As[srow][sseg * 8] = a0;
        *(bf16x8*)&As[srow + 64][sseg * 8] = a1;
        *(bf16x8*)&Bs[srow][sseg * 8] = b0;
        *(bf16x8*)&Bs[srow + 64][sseg * 8] = b1;
        __syncthreads();
        if (kt < 15) {
            int ko = (kt + 1) * 32;
            a0 = *(const bf16x8*)(Ap0 + ko);
            a1 = *(const bf16x8*)(Ap1 + ko);
            b0 = *(const bf16x8*)(Wp0 + ko);
            b1 = *(const bf16x8*)(Wp1 + ko);
        }
        bf16x8 ar[4], br[4];
#pragma unroll
        for (int i = 0; i < 4; ++i) ar[i] = *(const bf16x8*)&As[rbase + 16 * i + cl][quad * 8];
#pragma unroll
        for (int j = 0; j < 4; ++j) br[j] = *(const bf16x8*)&Bs[cbase + 16 * j + cl][quad * 8];
#pragma unroll
        for (int i = 0; i < 4; ++i)
#pragma unroll
            for (int j = 0; j < 4; ++j)
                acc[i][j] = __builtin_amdgcn_mfma_f32_16x16x32_bf16(ar[i], br[j], acc[i][j], 0, 0, 0);
    }
    float bv[4];
#pragma unroll
    for (int j = 0; j < 4; ++j) bv[j] = bias ? bias[o0 + cbase + 16 * j + cl] : 0.0f;
#pragma unroll
    for (int i = 0; i < 4; ++i) {
#pragma unroll
        for (int r = 0; r < 4; ++r) {
            int n = n0 + rbase + 16 * i + quad * 4 + r;
            if (n >= N) continue;
#pragma unroll
            for (int j = 0; j < 4; ++j) {
                float v = (acc[i][j][r] + bv[j]) * scale;
                int o = o0 + cbase + 16 * j + cl;
                if (Cb) Cb[(long)n * NE + o] = cvt_bf16(v);
                else    Cf[(long)n * NE + o] = v;
            }
        }
    }
}

__global__ __launch_bounds__(256) void gemm_qkv(
    const short* __restrict__ A,
    const short* __restrict__ W0, const short* __restrict__ W1, const short* __restrict__ W2,
    const float* __restrict__ b0, const float* __restrict__ b1, const float* __restrict__ b2,
    short* __restrict__ C0, short* __restrict__ C1, short* __restrict__ C2, int N) {
    int z = blockIdx.z;
    const short* W = z == 0 ? W0 : z == 1 ? W1 : W2;
    const float* bb = z == 0 ? b0 : z == 1 ? b1 : b2;
    short* C = z == 0 ? C0 : z == 1 ? C1 : C2;
    gemm_core(A, W, bb, z == 0 ? 0.125f : 1.0f, C, nullptr, N);
}

__global__ __launch_bounds__(256) void gemm_out(
    const short* __restrict__ A, const short* __restrict__ W,
    float* __restrict__ C, int N) {
    gemm_core(A, W, nullptr, 1.0f, nullptr, C, N);
}

// ---------------- MFMA flash attention: register-resident P (S^T trick) ----------------
// S^T = K.Q^T via mfma_16x16x32 (C rows = key, cols = q). Its C-layout IS the
// B-operand layout of mfma_16x16x16bf16_1k, so P never touches LDS:
// O^T = V^T.P^T accumulated per 16-d tile. l is per-lane (q=lane&15).
// Vt swizzled at 4-short granularity: col-group g' = g ^ ((d>>2)&15).
// R1: 128 q-rows per block (2 q-subtiles u=0,1 per wave).
// R3: KEY-SPLIT (flash-decoding): blockIdx.z = b*2+half; each block does half
// the K/V tiles (17 or 16), writes UNNORMALIZED fp32 partial O + partial l.
// R4: QPAD=2176 (grid q-extent) + q<NF guard on partial writes.
// R5: NO min-waves clamp in launch_bounds — (256,4) forced VGPR=64 -> spills.
// R6: P packing via v_cvt_pk_bf16_f32 (2 insts vs ~16): VALU was the critical
// pipe (VALUBusy 34% > MfmaUtil 31%).
__global__ __launch_bounds__(256) void fattn_mfma(
    const short* __restrict__ Qr, const short* __restrict__ Qi,
    const short* __restrict__ Kr, const short* __restrict__ Ki,
    const short* __restrict__ Vr, const short* __restrict__ Vi,
    float* __restrict__ Opr, float* __restrict__ Opi, float* __restrict__ lsp) {
    __shared__ short Ks[2][64][72];   // [r/i][key][d]
    __shared__ short Vt[2][64][72];   // [r/i][d][key 4-swizzled]
    int tid = threadIdx.x;
    int wv = tid >> 6, lane = tid & 63;
    int quad = lane >> 4, cl = lane & 15;
    int h = blockIdx.y;
    int zz = blockIdx.z;
    int b = zz >> 1, half = zz & 1;
    long base = (long)b * NF * NE + h * ND;
    int qbase = blockIdx.x * 128 + wv * 32;
    int kt0 = half * 17;
    int ktN = half ? 33 : 17;

    int sk0 = (tid >> 4) << 2;   // staged keys (group g0 = tid>>4)
    int sd0 = (tid & 15) << 2;   // staged dims
    int g0 = tid >> 4;
    int dsw = tid & 15;          // (d>>2) for all 4 staged dim rows

    // ---- Q fragments: B-operand of S^T (B[k=d][n=q]), pre-scaled by 1/8 ----
    bf16x8 qar[2][2], qai[2][2];
#pragma unroll
    for (int u = 0; u < 2; ++u) {
        int qrow = qbase + 16 * u + cl; if (qrow >= NF) qrow = NF - 1;
        const short* pr = Qr + base + (long)qrow * NE + 8 * quad;
        const short* pi = Qi + base + (long)qrow * NE + 8 * quad;
        qar[u][0] = *(const bf16x8*)pr;
        qar[u][1] = *(const bf16x8*)(pr + 32);
        qai[u][0] = *(const bf16x8*)pi;
        qai[u][1] = *(const bf16x8*)(pi + 32);
    }

    float ls[2] = {0.f, 0.f};
    f32x4 Or2[4][2], Oi2[4][2];   // O^T tiles: rows d=16nt+quad*4+r, col q=16u+cl
#pragma unroll
    for (int t = 0; t < 4; ++t)
#pragma unroll
        for (int u = 0; u < 2; ++u) {
            Or2[t][u] = (f32x4){0, 0, 0, 0};
            Oi2[t][u] = (f32x4){0, 0, 0, 0};
        }

    short4v lk0[4], lk1[4], lv0[4], lv1[4];
    const long TSTEP = (long)64 * NE;
    const short* pKr = Kr + base + (long)sk0 * NE + sd0 + (long)kt0 * TSTEP;
    const short* pKi = Ki + base + (long)sk0 * NE + sd0 + (long)kt0 * TSTEP;
    const short* pVr = Vr + base + (long)sk0 * NE + sd0 + (long)kt0 * TSTEP;
    const short* pVi = Vi + base + (long)sk0 * NE + sd0 + (long)kt0 * TSTEP;

    auto ldfull = [&]() {
#pragma unroll
        for (int kk = 0; kk < 4; ++kk) {
            long o = (long)kk * NE;
            lk0[kk] = *(const short4v*)(pKr + o);
            lk1[kk] = *(const short4v*)(pKi + o);
            lv0[kk] = *(const short4v*)(pVr + o);
            lv1[kk] = *(const short4v*)(pVi + o);
        }
        pKr += TSTEP; pKi += TSTEP; pVr += TSTEP; pVi += TSTEP;
    };
    auto ldmask = [&]() {   // tile 32: keys 2048..2111, mask >= NF
        short4v z4 = {0, 0, 0, 0};
#pragma unroll
        for (int kk = 0; kk < 4; ++kk) {
            int mg = 2048 + sk0 + kk;
            if (mg < NF) {
                long o = (long)kk * NE;
                lk0[kk] = *(const short4v*)(pKr + o);
                lk1[kk] = *(const short4v*)(pKi + o);
                lv0[kk] = *(const short4v*)(pVr + o);
                lv1[kk] = *(const short4v*)(pVi + o);
            } else { lk0[kk] = z4; lk1[kk] = z4; lv0[kk] = z4; lv1[kk] = z4; }
        }
    };
    ldfull();   // regs <- tile kt0

    for (int kt = kt0; kt < ktN; ++kt) {
        __syncthreads();
        // ---- stage K (row-major) + V (transposed, 4-granular XOR swizzle) ----
#pragma unroll
        for (int kk = 0; kk < 4; ++kk) {
            *(short4v*)&Ks[0][sk0 + kk][sd0] = lk0[kk];
            *(short4v*)&Ks[1][sk0 + kk][sd0] = lk1[kk];
        }
        {
            int cv = (g0 ^ dsw) << 2;
#pragma unroll
            for (int dd = 0; dd < 4; ++dd) {
                short4v t0 = {lv0[0][dd], lv0[1][dd], lv0[2][dd], lv0[3][dd]};
                *(short4v*)&Vt[0][sd0 + dd][cv] = t0;
                short4v t1 = {lv1[0][dd], lv1[1][dd], lv1[2][dd], lv1[3][dd]};
                *(short4v*)&Vt[1][sd0 + dd][cv] = t1;
            }
        }
        __syncthreads();
        if (kt + 1 < ktN) {                 // prefetch next tile into regs
            if (kt + 1 < 32) ldfull();
            else ldmask();
        }

        // ---- S^T = K.Q^T (32 MFMAs): c[t][u] rows = key quad*4+r, col = q ----
        f32x4 c[4][2];
        __builtin_amdgcn_s_setprio(1);
#pragma unroll
        for (int t = 0; t < 4; ++t) {
            const short* kr = &Ks[0][cl + 16 * t][8 * quad];
            const short* ki = &Ks[1][cl + 16 * t][8 * quad];
            bf16x8 k0 = *(const bf16x8*)kr;
            bf16x8 k1 = *(const bf16x8*)(kr + 32);
            bf16x8 k2 = *(const bf16x8*)ki;
            bf16x8 k3 = *(const bf16x8*)(ki + 32);
#pragma unroll
            for (int u = 0; u < 2; ++u) {
                f32x4 acc = (f32x4){0, 0, 0, 0};
                acc = __builtin_amdgcn_mfma_f32_16x16x32_bf16(k0, qar[u][0], acc, 0, 0, 0);
                acc = __builtin_amdgcn_mfma_f32_16x16x32_bf16(k1, qar[u][1], acc, 0, 0, 0);
                acc = __builtin_amdgcn_mfma_f32_16x16x32_bf16(k2, qai[u][0], acc, 0, 0, 0);
                acc = __builtin_amdgcn_mfma_f32_16x16x32_bf16(k3, qai[u][1], acc, 0, 0, 0);
                c[t][u] = acc;
            }
        }
        __builtin_amdgcn_s_setprio(0);

        // ---- exp (no max-sub: |s|<~5), per-lane l, pack via v_cvt_pk ----
        short4v pb[4][2];
        if (kt < 32) {   // all 64 keys valid: branch-free
#pragma unroll
            for (int t = 0; t < 4; ++t)
#pragma unroll
                for (int u = 0; u < 2; ++u) {
                    float p0 = __expf(c[t][u][0]);
                    float p1 = __expf(c[t][u][1]);
                    float p2 = __expf(c[t][u][2]);
                    float p3 = __expf(c[t][u][3]);
                    ls[u] += (p0 + p1) + (p2 + p3);
                    pb[t][u] = pk4(p0, p1, p2, p3);
                }
        } else {         // tail tile: mask keys >= NF
#pragma unroll
            for (int t = 0; t < 4; ++t) {
                int kbase = 2048 + 16 * t + quad * 4;
#pragma unroll
                for (int u = 0; u < 2; ++u) {
                    float p0 = (kbase + 0 < NF) ? __expf(c[t][u][0]) : 0.0f;
                    float p1 = (kbase + 1 < NF) ? __expf(c[t][u][1]) : 0.0f;
                    float p2 = (kbase + 2 < NF) ? __expf(c[t][u][2]) : 0.0f;
                    float p3 = (kbase + 3 < NF) ? __expf(c[t][u][3]) : 0.0f;
                    ls[u] += (p0 + p1) + (p2 + p3);
                    pb[t][u] = pk4(p0, p1, p2, p3);
                }
            }
        }

        // ---- O^T += V^T.P^T  (64 mfma_16x16x16, P in registers) ----
        __builtin_amdgcn_s_setprio(1);
#pragma unroll
        for (int nt = 0; nt < 4; ++nt) {
            int d = cl + 16 * nt;
            int dg = (d >> 2) & 15;
#pragma unroll
            for (int t = 0; t < 4; ++t) {
                int g = 4 * t + quad;
                int cv = ((g ^ dg) << 2);
                short4v va = *(const short4v*)&Vt[0][d][cv];
                short4v vb = *(const short4v*)&Vt[1][d][cv];
#pragma unroll
                for (int u = 0; u < 2; ++u) {
                    Or2[nt][u] = __builtin_amdgcn_mfma_f32_16x16x16bf16_1k(va, pb[t][u], Or2[nt][u], 0, 0, 0);
                    Oi2[nt][u] = __builtin_amdgcn_mfma_f32_16x16x16bf16_1k(vb, pb[t][u], Oi2[nt][u], 0, 0, 0);
                }
            }
        }
        __builtin_amdgcn_s_setprio(0);
    }

    // ---- l reduce over quads, write UNNORMALIZED partials (fp32), q<NF only ----
    long ob = ((long)(half * NB + b) * NH + h) * ((long)QPAD * 64);
    long lb = ((long)(half * NB + b) * NH + h) * QPAD;
#pragma unroll
    for (int u = 0; u < 2; ++u) {
        float l2 = ls[u];
        l2 += __shfl_xor(l2, 16);
        l2 += __shfl_xor(l2, 32);
        int q = qbase + 16 * u + cl;
        if (q < NF) {
            if (quad == 0) lsp[lb + q] = l2;
            float* pr = Opr + ob + (long)q * 64;
            float* pi2 = Opi + ob + (long)q * 64;
#pragma unroll
            for (int nt = 0; nt < 4; ++nt) {
                int d0 = 16 * nt + quad * 4;
                *(f32x4*)(pr + d0) = Or2[nt][u];
                *(f32x4*)(pi2 + d0) = Oi2[nt][u];
            }
        }
    }
}

extern "C" void kernel_launch(void* const* d_in, const int* in_sizes, int n_in,
                              void* d_out, int out_size, void* d_ws, size_t ws_size,
                              hipStream_t stream) {
    const float* x   = (const float*)d_in[0];
    const float* g   = (const float*)d_in[1];
    const float* be  = (const float*)d_in[2];
    const float* Wqr = (const float*)d_in[3];
    const float* bqr = (const float*)d_in[4];
    const float* Wqi = (const float*)d_in[5];
    const float* bqi = (const float*)d_in[6];
    const float* Wkr = (const float*)d_in[7];
    const float* bkr = (const float*)d_in[8];
    const float* Wki = (const float*)d_in[9];
    const float* bki = (const float*)d_in[10];
    const float* Wvr = (const float*)d_in[11];
    const float* bvr = (const float*)d_in[12];
    const float* Wvi = (const float*)d_in[13];
    const float* bvi = (const float*)d_in[14];
    const float* Wo  = (const float*)d_in[15];
    float* out = (float*)d_out;

    const long SZ_T = (long)NB * NL * NE;  // 8,388,608
    const long SZ_F = (long)NB * NF * NE;  // 4,196,352
    float2* twg = (float2*)d_ws;            // 2048 float2
    short* xnb = (short*)(twg + 2048);      // bf16 region
    short* xr  = xnb + SZ_T;
    short* xi  = xr + SZ_F;
    short* Qr  = xi + SZ_F;
    short* Qi  = Qr + SZ_F;
    short* Kr  = Qi + SZ_F;
    short* Ki  = Kr + SZ_F;
    short* Vr  = Ki + SZ_F;
    short* Vi  = Vr + SZ_F;
    short* Orb = Vi + SZ_F;                 // (unused since R6; layout kept)
    short* Oib = Orb + SZ_F;                // (unused since R6; layout kept)
    short* yt  = Oib + SZ_F;                // SZ_T bf16
    short* wb  = yt + SZ_T;                 // 7 * WSZ bf16
    float* Opr = (float*)(wb + 7L * WSZ);   // 2 halves x NB x NH x QPAD x 64 f32
    float* Opi = Opr + 2 * OPSZ;
    float* lsp = Opi + 2 * OPSZ;            // 2 x NB x NH x QPAD f32
    (void)Orb; (void)Oib;

    twiddle_kernel<<<NL / 2 / 256, 256, 0, stream>>>(twg);
    castw_kernel<<<dim3(WSZ / 1024, 7), 256, 0, stream>>>(Wqr, Wqi, Wkr, Wki, Wvr, Wvi, Wo, wb);
    ln_kernel<<<NB * NL / 4, 256, 0, stream>>>(x, g, be, xnb);
    rfft_pair<<<NB * 256, 256, 0, stream>>>(xnb, twg, xr, xi);
    int Nf = NB * NF;                       // 8196
    dim3 gq(NE / 128, (Nf + 127) / 128, 3);
    gemm_qkv<<<gq, 256, 0, stream>>>(xr, wb + 0L * WSZ, wb + 2L * WSZ, wb + 4L * WSZ,
                                     bqr, bkr, bvr, Qr, Kr, Vr, Nf);
    gemm_qkv<<<gq, 256, 0, stream>>>(xi, wb + 1L * WSZ, wb + 3L * WSZ, wb + 5L * WSZ,
                                     bqi, bki, bvi, Qi, Ki, Vi, Nf);
    fattn_mfma<<<dim3(17, NH, NB * 2), 256, 0, stream>>>(Qr, Qi, Kr, Ki, Vr, Vi, Opr, Opi, lsp);
    irfft_pair<<<NB * 256, 256, 0, stream>>>(Opr, Opi, lsp, twg, yt);
    gemm_out<<<dim3(NE / 128, NB * NL / 128), 256, 0, stream>>>(yt, wb + 6L * WSZ, out, NB * NL);
}

// Round 8
// 410.755 us; speedup vs baseline: 2.0842x; 1.0460x over previous
//
#include <hip/hip_runtime.h>
#include <math.h>

#define NB 4
#define NL 4096
#define NE 512
#define NH 8
#define ND 64
#define NF 2049      // NL/2 + 1
#define WSZ (NE * NE) // 262144 elements per weight matrix
#define QPAD 2176    // q rows padded to 17*128 (grid extent!)
#define OPSZ ((long)NB * NH * QPAD * 64)   // one half-partial component

static constexpr float INV_SQRT_N = 1.0f / 64.0f;   // 1/sqrt(4096), ortho norm

typedef __attribute__((ext_vector_type(8))) short bf16x8;
typedef __attribute__((ext_vector_type(4))) short short4v;
typedef __attribute__((ext_vector_type(4))) float f32x4;

__device__ __forceinline__ float2 cmul(float2 a, float2 b) {
    return make_float2(a.x * b.x - a.y * b.y, a.x * b.y + a.y * b.x);
}

__device__ __forceinline__ short cvt_bf16(float f) {
    unsigned u = __float_as_uint(f);
    unsigned r = (u + 0x7FFFu + ((u >> 16) & 1u)) >> 16;
    return (short)r;
}

__device__ __forceinline__ int pack_bf16x2(float a, float b) {
    return (int)(unsigned short)cvt_bf16(a) | ((int)(unsigned short)cvt_bf16(b) << 16);
}

// HW packed f32->bf16 (RTNE), 1 inst per pair (T12 primitive, gfx950-verified)
__device__ __forceinline__ short4v pk4(float a, float b, float c, float d) {
    union { unsigned u[2]; short4v s; } r;
    asm("v_cvt_pk_bf16_f32 %0, %1, %2" : "=v"(r.u[0]) : "v"(a), "v"(b));
    asm("v_cvt_pk_bf16_f32 %0, %1, %2" : "=v"(r.u[1]) : "v"(c), "v"(d));
    return r.s;
}

// async global->LDS, 16B per lane: data lands at ldsbase + lane*16
__device__ __forceinline__ void load_lds16(const void* g, void* l) {
    __builtin_amdgcn_global_load_lds(
        (const __attribute__((address_space(1))) void*)g,
        (__attribute__((address_space(3))) void*)l, 16, 0, 0);
}

__device__ __forceinline__ float2 unpk(int v) {
    return make_float2(__uint_as_float(((unsigned)v & 0xffffu) << 16),
                       __uint_as_float((unsigned)v & 0xffff0000u));
}

// base-4 digit reversal of a 12-bit index
__device__ __forceinline__ int b4rev(int t) {
    int r = __brev((unsigned)t) >> 20;
    return ((r & 0x555) << 1) | ((r & 0xAAA) >> 1);
}

// ---------------- one-time exact twiddles ----------------
__global__ __launch_bounds__(256) void twiddle_kernel(float2* __restrict__ twg) {
    int j = blockIdx.x * 256 + threadIdx.x;
    double ang = (2.0 * M_PI / (double)NL) * (double)j;
    double s, c;
    sincos(ang, &s, &c);
    twg[j] = make_float2((float)c, (float)s);
}

// ---------------- one-time weight cast fp32 -> bf16 (7 matrices) ----------------
__global__ __launch_bounds__(256) void castw_kernel(
    const float* __restrict__ w0, const float* __restrict__ w1,
    const float* __restrict__ w2, const float* __restrict__ w3,
    const float* __restrict__ w4, const float* __restrict__ w5,
    const float* __restrict__ w6, short* __restrict__ dst) {
    int which = blockIdx.y;
    const float* s = which == 0 ? w0 : which == 1 ? w1 : which == 2 ? w2 :
                     which == 3 ? w3 : which == 4 ? w4 : which == 5 ? w5 : w6;
    long i = (long)blockIdx.x * 1024 + threadIdx.x * 4;
    float4 v = *(const float4*)(s + i);
    short4v o = {cvt_bf16(v.x), cvt_bf16(v.y), cvt_bf16(v.z), cvt_bf16(v.w)};
    *(short4v*)(dst + (long)which * WSZ + i) = o;
}

// ---------------- LayerNorm: one row (512) per wave, bf16 output ----------------
__global__ __launch_bounds__(256) void ln_kernel(
    const float* __restrict__ x, const float* __restrict__ g,
    const float* __restrict__ be, short* __restrict__ xnb) {
    int wv = threadIdx.x >> 6, lane = threadIdx.x & 63;
    long row = (long)blockIdx.x * 4 + wv;
    const float* xp = x + row * NE + lane * 8;
    float4 a = *(const float4*)xp;
    float4 b = *(const float4*)(xp + 4);
    float s  = a.x + a.y + a.z + a.w + b.x + b.y + b.z + b.w;
    float ss = a.x * a.x + a.y * a.y + a.z * a.z + a.w * a.w
             + b.x * b.x + b.y * b.y + b.z * b.z + b.w * b.w;
#pragma unroll
    for (int o = 32; o; o >>= 1) { s += __shfl_xor(s, o); ss += __shfl_xor(ss, o); }
    float mu = s * (1.0f / NE);
    float var = ss * (1.0f / NE) - mu * mu;
    float rs = rsqrtf(var + 1e-5f);
    const float* gp = g + lane * 8;
    const float* bp = be + lane * 8;
    float4 g0 = *(const float4*)gp, g1 = *(const float4*)(gp + 4);
    float4 b0 = *(const float4*)bp, b1 = *(const float4*)(bp + 4);
    bf16x8 ov;
    ov[0] = cvt_bf16((a.x - mu) * rs * g0.x + b0.x);
    ov[1] = cvt_bf16((a.y - mu) * rs * g0.y + b0.y);
    ov[2] = cvt_bf16((a.z - mu) * rs * g0.z + b0.z);
    ov[3] = cvt_bf16((a.w - mu) * rs * g0.w + b0.w);
    ov[4] = cvt_bf16((b.x - mu) * rs * g1.x + b1.x);
    ov[5] = cvt_bf16((b.y - mu) * rs * g1.y + b1.y);
    ov[6] = cvt_bf16((b.z - mu) * rs * g1.z + b1.z);
    ov[7] = cvt_bf16((b.w - mu) * rs * g1.w + b1.w);
    *(bf16x8*)(xnb + row * NE + lane * 8) = ov;
}

// ---------------- radix-4 FFT stages in LDS (4096 pts, 6 stages) ----------------
template <int INV>
__device__ __forceinline__ void fft4_stages(float2* sdata, const float2* tws, int tid) {
#pragma unroll
    for (int st = 0; st < 6; ++st) {
        __syncthreads();
        int Q = 1 << (2 * st);
        int tq = 10 - 2 * st;
#pragma unroll
        for (int jj = 0; jj < 4; ++jj) {
            int j = tid + jj * 256;
            int k = j & (Q - 1);
            int i0 = ((j >> (2 * st)) << (2 * st + 2)) | k;
            float2 w1 = tws[k << tq];
            float2 w2 = tws[(2 * k) << tq];
            float2 w3 = cmul(w1, w2);
            float2 a = sdata[i0];
            float2 b = cmul(w1, sdata[i0 + Q]);
            float2 c = cmul(w2, sdata[i0 + 2 * Q]);
            float2 d = cmul(w3, sdata[i0 + 3 * Q]);
            float2 t0 = make_float2(a.x + c.x, a.y + c.y);
            float2 t1 = make_float2(a.x - c.x, a.y - c.y);
            float2 t2 = make_float2(b.x + d.x, b.y + d.y);
            float2 bd = make_float2(b.x - d.x, b.y - d.y);
            float2 t3 = INV ? make_float2(-bd.y, bd.x) : make_float2(bd.y, -bd.x);
            sdata[i0]         = make_float2(t0.x + t2.x, t0.y + t2.y);
            sdata[i0 + Q]     = make_float2(t1.x + t3.x, t1.y + t3.y);
            sdata[i0 + 2 * Q] = make_float2(t0.x - t2.x, t0.y - t2.y);
            sdata[i0 + 3 * Q] = make_float2(t1.x - t3.x, t1.y - t3.y);
        }
    }
    __syncthreads();
}

// XCD-aware e-pair swizzle: consecutive dispatch ids (round-robin over 8 XCDs)
// map to e-stripes 32 pairs apart, so each XCD owns a contiguous 64-column band.
__device__ __forceinline__ int ep_swizzle(int loc) {
    return ((loc & 7) << 5) | (loc >> 3);
}

// ---------------- forward rfft: 2 real bf16 columns in 1 complex FFT ----------------
__global__ __launch_bounds__(256) void rfft_pair(
    const short* __restrict__ xnb, const float2* __restrict__ twg,
    short* __restrict__ xr, short* __restrict__ xi) {
    __shared__ float2 sdata[NL];
    __shared__ float2 tws[NL / 2];
    int b = blockIdx.x >> 8;
    int e0 = ep_swizzle(blockIdx.x & 255) * 2;
    int tid = threadIdx.x;
    const short* xp = xnb + (long)b * NL * NE + e0;
#pragma unroll
    for (int jj = 0; jj < 16; ++jj) {
        int t = tid + jj * 256;
        int v = *(const int*)(xp + (long)t * NE);
        sdata[b4rev(t)] = unpk(v);
    }
#pragma unroll
    for (int jj = 0; jj < 8; ++jj) {
        int j = tid + jj * 256;
        float2 w = twg[j];
        tws[j] = make_float2(w.x, -w.y);   // forward: e^{-i theta}
    }
    fft4_stages<0>(sdata, tws, tid);
    short* xrp = xr + (long)b * NF * NE + e0;
    short* xip = xi + (long)b * NF * NE + e0;
    for (int f = tid; f < NF; f += 256) {
        int M = (NL - f) & (NL - 1);
        float2 zf = sdata[f], zm = sdata[M];
        float re0 = (zf.x + zm.x) * (0.5f * INV_SQRT_N);
        float im0 = (zf.y - zm.y) * (0.5f * INV_SQRT_N);
        float re1 = (zf.y + zm.y) * (0.5f * INV_SQRT_N);
        float im1 = (zm.x - zf.x) * (0.5f * INV_SQRT_N);
        *(int*)(xrp + (long)f * NE) = pack_bf16x2(re0, re1);
        *(int*)(xip + (long)f * NE) = pack_bf16x2(im0, im1);
    }
}

// ---------------- inverse rfft, FUSED with key-half combine (R6) ----------------
__global__ __launch_bounds__(256) void irfft_pair(
    const float* __restrict__ Opr, const float* __restrict__ Opi,
    const float* __restrict__ lsp, const float2* __restrict__ twg,
    short* __restrict__ yt) {
    __shared__ float2 sdata[NL];
    __shared__ float2 tws[NL / 2];
    int b = blockIdx.x >> 8;
    int e0 = ep_swizzle(blockIdx.x & 255) * 2;
    int tid = threadIdx.x;
    int h = e0 >> 6, d0 = e0 & 63;
    long p0 = ((long)b * NH + h) * ((long)QPAD * 64) + d0;
    long p1 = ((long)(NB + b) * NH + h) * ((long)QPAD * 64) + d0;
    long l0 = ((long)b * NH + h) * QPAD;
    long l1 = ((long)(NB + b) * NH + h) * QPAD;
    for (int f = tid; f < NF; f += 256) {
        float l = lsp[l0 + f] + lsp[l1 + f];
        float inv = 1.0f / l;
        float2 r1 = *(const float2*)(Opr + p0 + (long)f * 64);
        float2 r2 = *(const float2*)(Opr + p1 + (long)f * 64);
        float2 i1 = *(const float2*)(Opi + p0 + (long)f * 64);
        float2 i2 = *(const float2*)(Opi + p1 + (long)f * 64);
        float2 vr = make_float2((r1.x + r2.x) * inv, (r1.y + r2.y) * inv);
        float2 vi = make_float2((i1.x + i2.x) * inv, (i1.y + i2.y) * inv);
        if (f == 0 || f == NL / 2) vi = make_float2(0.f, 0.f);  // C2R ignores these
        sdata[b4rev(f)] = make_float2(vr.x - vi.y, vi.x + vr.y);
        if (f > 0 && f < NL / 2) {
            sdata[b4rev(NL - f)] = make_float2(vr.x + vi.y, vr.y - vi.x);
        }
    }
#pragma unroll
    for (int jj = 0; jj < 8; ++jj) {
        int j = tid + jj * 256;
        tws[j] = twg[j];                   // inverse: e^{+i theta}
    }
    fft4_stages<1>(sdata, tws, tid);
    short* yp = yt + (long)b * NL * NE + e0;
#pragma unroll
    for (int jj = 0; jj < 16; ++jj) {
        int t = tid + jj * 256;
        float2 z = sdata[t];
        *(int*)(yp + (long)t * NE) = pack_bf16x2(z.x * INV_SQRT_N, z.y * INV_SQRT_N);
    }
}

// ---------------- bf16 MFMA GEMM core (R7: global_load_lds staging) ----------------
// LDS tiles unpadded [128][32] (64B rows) — required by global_load_lds's
// linear base+lane*16 dest. Wave wv stages rows [wv*32, wv*32+32): 2 gload_lds
// per matrix per K-step, no VGPR round-trip, no ds_writes. MFMA frag b128
// reads at 64B stride are a bijective lane->(row,slot) map over 1KB -> runs
// at the 8-cyc structural floor (no conflict regression vs padded).
__device__ __forceinline__ void gemm_core(
    const short* __restrict__ A, const short* __restrict__ W,
    const float* __restrict__ bias, float scale, short* __restrict__ Cb,
    float* __restrict__ Cf, int N) {
    __shared__ short As[128][32];
    __shared__ short Bs[128][32];
    int o0 = blockIdx.x * 128;
    int n0 = blockIdx.y * 128;
    int tid = threadIdx.x;
    int lane = tid & 63, wv = tid >> 6;
    int quad = lane >> 4, cl = lane & 15;
    int rbase = (wv >> 1) << 6;
    int cbase = (wv & 1) << 6;

    // staging geometry: lane l -> row wv*32 + (l>>2) (+16 for 2nd instr), col (l&3)*8
    int srow = wv * 32 + (lane >> 2);
    int scol = (lane & 3) * 8;
    int ra0 = n0 + srow;      if (ra0 >= N) ra0 = N - 1;
    int ra1 = n0 + srow + 16; if (ra1 >= N) ra1 = N - 1;
    const short* Asrc0 = A + (long)ra0 * NE + scol;
    const short* Asrc1 = A + (long)ra1 * NE + scol;
    const short* Wsrc0 = W + (long)(o0 + srow) * NE + scol;
    const short* Wsrc1 = W + (long)(o0 + srow + 16) * NE + scol;
    short* Adst0 = &As[wv * 32][0];
    short* Adst1 = &As[wv * 32 + 16][0];
    short* Bdst0 = &Bs[wv * 32][0];
    short* Bdst1 = &Bs[wv * 32 + 16][0];

    f32x4 acc[4][4];
#pragma unroll
    for (int i = 0; i < 4; ++i)
#pragma unroll
        for (int j = 0; j < 4; ++j) acc[i][j] = (f32x4){0, 0, 0, 0};

    for (int kt = 0; kt < 16; ++kt) {
        __syncthreads();
        load_lds16(Asrc0, Adst0);
        load_lds16(Asrc1, Adst1);
        load_lds16(Wsrc0, Bdst0);
        load_lds16(Wsrc1, Bdst1);
        Asrc0 += 32; Asrc1 += 32; Wsrc0 += 32; Wsrc1 += 32;
        __syncthreads();   // compiler drains vmcnt(0) before the barrier
        bf16x8 ar[4], br[4];
#pragma unroll
        for (int i = 0; i < 4; ++i) ar[i] = *(const bf16x8*)&As[rbase + 16 * i + cl][quad * 8];
#pragma unroll
        for (int j = 0; j < 4; ++j) br[j] = *(const bf16x8*)&Bs[cbase + 16 * j + cl][quad * 8];
#pragma unroll
        for (int i = 0; i < 4; ++i)
#pragma unroll
            for (int j = 0; j < 4; ++j)
                acc[i][j] = __builtin_amdgcn_mfma_f32_16x16x32_bf16(ar[i], br[j], acc[i][j], 0, 0, 0);
    }
    float bv[4];
#pragma unroll
    for (int j = 0; j < 4; ++j) bv[j] = bias ? bias[o0 + cbase + 16 * j + cl] : 0.0f;
#pragma unroll
    for (int i = 0; i < 4; ++i) {
#pragma unroll
        for (int r = 0; r < 4; ++r) {
            int n = n0 + rbase + 16 * i + quad * 4 + r;
            if (n >= N) continue;
#pragma unroll
            for (int j = 0; j < 4; ++j) {
                float v = (acc[i][j][r] + bv[j]) * scale;
                int o = o0 + cbase + 16 * j + cl;
                if (Cb) Cb[(long)n * NE + o] = cvt_bf16(v);
                else    Cf[(long)n * NE + o] = v;
            }
        }
    }
}

// R7: single launch covers all 6 QKV GEMMs: z%3 = comp(q,k,v), z/3 = im(r,i)
__global__ __launch_bounds__(256) void gemm_qkv(
    const short* __restrict__ Ar, const short* __restrict__ Ai,
    const short* __restrict__ wb,
    const float* __restrict__ bqr, const float* __restrict__ bqi,
    const float* __restrict__ bkr, const float* __restrict__ bki,
    const float* __restrict__ bvr, const float* __restrict__ bvi,
    short* __restrict__ Qr, short* __restrict__ Qi,
    short* __restrict__ Kr, short* __restrict__ Ki,
    short* __restrict__ Vr, short* __restrict__ Vi, int N) {
    int z = blockIdx.z;
    int comp = z % 3, im = z / 3;
    const short* A = im ? Ai : Ar;
    const short* W = wb + (long)(comp * 2 + im) * WSZ;
    const float* bb = comp == 0 ? (im ? bqi : bqr)
                    : comp == 1 ? (im ? bki : bkr)
                                : (im ? bvi : bvr);
    short* C = comp == 0 ? (im ? Qi : Qr)
             : comp == 1 ? (im ? Ki : Kr)
                         : (im ? Vi : Vr);
    gemm_core(A, W, bb, comp == 0 ? 0.125f : 1.0f, C, nullptr, N);
}

__global__ __launch_bounds__(256) void gemm_out(
    const short* __restrict__ A, const short* __restrict__ W,
    float* __restrict__ C, int N) {
    gemm_core(A, W, nullptr, 1.0f, nullptr, C, N);
}

// ---------------- MFMA flash attention: register-resident P (S^T trick) ----------------
// (unchanged from R6)
__global__ __launch_bounds__(256) void fattn_mfma(
    const short* __restrict__ Qr, const short* __restrict__ Qi,
    const short* __restrict__ Kr, const short* __restrict__ Ki,
    const short* __restrict__ Vr, const short* __restrict__ Vi,
    float* __restrict__ Opr, float* __restrict__ Opi, float* __restrict__ lsp) {
    __shared__ short Ks[2][64][72];   // [r/i][key][d]
    __shared__ short Vt[2][64][72];   // [r/i][d][key 4-swizzled]
    int tid = threadIdx.x;
    int wv = tid >> 6, lane = tid & 63;
    int quad = lane >> 4, cl = lane & 15;
    int h = blockIdx.y;
    int zz = blockIdx.z;
    int b = zz >> 1, half = zz & 1;
    long base = (long)b * NF * NE + h * ND;
    int qbase = blockIdx.x * 128 + wv * 32;
    int kt0 = half * 17;
    int ktN = half ? 33 : 17;

    int sk0 = (tid >> 4) << 2;   // staged keys (group g0 = tid>>4)
    int sd0 = (tid & 15) << 2;   // staged dims
    int g0 = tid >> 4;
    int dsw = tid & 15;          // (d>>2) for all 4 staged dim rows

    // ---- Q fragments: B-operand of S^T (B[k=d][n=q]), pre-scaled by 1/8 ----
    bf16x8 qar[2][2], qai[2][2];
#pragma unroll
    for (int u = 0; u < 2; ++u) {
        int qrow = qbase + 16 * u + cl; if (qrow >= NF) qrow = NF - 1;
        const short* pr = Qr + base + (long)qrow * NE + 8 * quad;
        const short* pi = Qi + base + (long)qrow * NE + 8 * quad;
        qar[u][0] = *(const bf16x8*)pr;
        qar[u][1] = *(const bf16x8*)(pr + 32);
        qai[u][0] = *(const bf16x8*)pi;
        qai[u][1] = *(const bf16x8*)(pi + 32);
    }

    float ls[2] = {0.f, 0.f};
    f32x4 Or2[4][2], Oi2[4][2];   // O^T tiles: rows d=16nt+quad*4+r, col q=16u+cl
#pragma unroll
    for (int t = 0; t < 4; ++t)
#pragma unroll
        for (int u = 0; u < 2; ++u) {
            Or2[t][u] = (f32x4){0, 0, 0, 0};
            Oi2[t][u] = (f32x4){0, 0, 0, 0};
        }

    short4v lk0[4], lk1[4], lv0[4], lv1[4];
    const long TSTEP = (long)64 * NE;
    const short* pKr = Kr + base + (long)sk0 * NE + sd0 + (long)kt0 * TSTEP;
    const short* pKi = Ki + base + (long)sk0 * NE + sd0 + (long)kt0 * TSTEP;
    const short* pVr = Vr + base + (long)sk0 * NE + sd0 + (long)kt0 * TSTEP;
    const short* pVi = Vi + base + (long)sk0 * NE + sd0 + (long)kt0 * TSTEP;

    auto ldfull = [&]() {
#pragma unroll
        for (int kk = 0; kk < 4; ++kk) {
            long o = (long)kk * NE;
            lk0[kk] = *(const short4v*)(pKr + o);
            lk1[kk] = *(const short4v*)(pKi + o);
            lv0[kk] = *(const short4v*)(pVr + o);
            lv1[kk] = *(const short4v*)(pVi + o);
        }
        pKr += TSTEP; pKi += TSTEP; pVr += TSTEP; pVi += TSTEP;
    };
    auto ldmask = [&]() {   // tile 32: keys 2048..2111, mask >= NF
        short4v z4 = {0, 0, 0, 0};
#pragma unroll
        for (int kk = 0; kk < 4; ++kk) {
            int mg = 2048 + sk0 + kk;
            if (mg < NF) {
                long o = (long)kk * NE;
                lk0[kk] = *(const short4v*)(pKr + o);
                lk1[kk] = *(const short4v*)(pKi + o);
                lv0[kk] = *(const short4v*)(pVr + o);
                lv1[kk] = *(const short4v*)(pVi + o);
            } else { lk0[kk] = z4; lk1[kk] = z4; lv0[kk] = z4; lv1[kk] = z4; }
        }
    };
    ldfull();   // regs <- tile kt0

    for (int kt = kt0; kt < ktN; ++kt) {
        __syncthreads();
        // ---- stage K (row-major) + V (transposed, 4-granular XOR swizzle) ----
#pragma unroll
        for (int kk = 0; kk < 4; ++kk) {
            *(short4v*)&Ks[0][sk0 + kk][sd0] = lk0[kk];
            *(short4v*)&Ks[1][sk0 + kk][sd0] = lk1[kk];
        }
        {
            int cv = (g0 ^ dsw) << 2;
#pragma unroll
            for (int dd = 0; dd < 4; ++dd) {
                short4v t0 = {lv0[0][dd], lv0[1][dd], lv0[2][dd], lv0[3][dd]};
                *(short4v*)&Vt[0][sd0 + dd][cv] = t0;
                short4v t1 = {lv1[0][dd], lv1[1][dd], lv1[2][dd], lv1[3][dd]};
                *(short4v*)&Vt[1][sd0 + dd][cv] = t1;
            }
        }
        __syncthreads();
        if (kt + 1 < ktN) {                 // prefetch next tile into regs
            if (kt + 1 < 32) ldfull();
            else ldmask();
        }

        // ---- S^T = K.Q^T (32 MFMAs): c[t][u] rows = key quad*4+r, col = q ----
        f32x4 c[4][2];
        __builtin_amdgcn_s_setprio(1);
#pragma unroll
        for (int t = 0; t < 4; ++t) {
            const short* kr = &Ks[0][cl + 16 * t][8 * quad];
            const short* ki = &Ks[1][cl + 16 * t][8 * quad];
            bf16x8 k0 = *(const bf16x8*)kr;
            bf16x8 k1 = *(const bf16x8*)(kr + 32);
            bf16x8 k2 = *(const bf16x8*)ki;
            bf16x8 k3 = *(const bf16x8*)(ki + 32);
#pragma unroll
            for (int u = 0; u < 2; ++u) {
                f32x4 acc = (f32x4){0, 0, 0, 0};
                acc = __builtin_amdgcn_mfma_f32_16x16x32_bf16(k0, qar[u][0], acc, 0, 0, 0);
                acc = __builtin_amdgcn_mfma_f32_16x16x32_bf16(k1, qar[u][1], acc, 0, 0, 0);
                acc = __builtin_amdgcn_mfma_f32_16x16x32_bf16(k2, qai[u][0], acc, 0, 0, 0);
                acc = __builtin_amdgcn_mfma_f32_16x16x32_bf16(k3, qai[u][1], acc, 0, 0, 0);
                c[t][u] = acc;
            }
        }
        __builtin_amdgcn_s_setprio(0);

        // ---- exp (no max-sub: |s|<~5), per-lane l, pack via v_cvt_pk ----
        short4v pb[4][2];
        if (kt < 32) {   // all 64 keys valid: branch-free
#pragma unroll
            for (int t = 0; t < 4; ++t)
#pragma unroll
                for (int u = 0; u < 2; ++u) {
                    float p0 = __expf(c[t][u][0]);
                    float p1 = __expf(c[t][u][1]);
                    float p2 = __expf(c[t][u][2]);
                    float p3 = __expf(c[t][u][3]);
                    ls[u] += (p0 + p1) + (p2 + p3);
                    pb[t][u] = pk4(p0, p1, p2, p3);
                }
        } else {         // tail tile: mask keys >= NF
#pragma unroll
            for (int t = 0; t < 4; ++t) {
                int kbase = 2048 + 16 * t + quad * 4;
#pragma unroll
                for (int u = 0; u < 2; ++u) {
                    float p0 = (kbase + 0 < NF) ? __expf(c[t][u][0]) : 0.0f;
                    float p1 = (kbase + 1 < NF) ? __expf(c[t][u][1]) : 0.0f;
                    float p2 = (kbase + 2 < NF) ? __expf(c[t][u][2]) : 0.0f;
                    float p3 = (kbase + 3 < NF) ? __expf(c[t][u][3]) : 0.0f;
                    ls[u] += (p0 + p1) + (p2 + p3);
                    pb[t][u] = pk4(p0, p1, p2, p3);
                }
            }
        }

        // ---- O^T += V^T.P^T  (64 mfma_16x16x16, P in registers) ----
        __builtin_amdgcn_s_setprio(1);
#pragma unroll
        for (int nt = 0; nt < 4; ++nt) {
            int d = cl + 16 * nt;
            int dg = (d >> 2) & 15;
#pragma unroll
            for (int t = 0; t < 4; ++t) {
                int g = 4 * t + quad;
                int cv = ((g ^ dg) << 2);
                short4v va = *(const short4v*)&Vt[0][d][cv];
                short4v vb = *(const short4v*)&Vt[1][d][cv];
#pragma unroll
                for (int u = 0; u < 2; ++u) {
                    Or2[nt][u] = __builtin_amdgcn_mfma_f32_16x16x16bf16_1k(va, pb[t][u], Or2[nt][u], 0, 0, 0);
                    Oi2[nt][u] = __builtin_amdgcn_mfma_f32_16x16x16bf16_1k(vb, pb[t][u], Oi2[nt][u], 0, 0, 0);
                }
            }
        }
        __builtin_amdgcn_s_setprio(0);
    }

    // ---- l reduce over quads, write UNNORMALIZED partials (fp32), q<NF only ----
    long ob = ((long)(half * NB + b) * NH + h) * ((long)QPAD * 64);
    long lb = ((long)(half * NB + b) * NH + h) * QPAD;
#pragma unroll
    for (int u = 0; u < 2; ++u) {
        float l2 = ls[u];
        l2 += __shfl_xor(l2, 16);
        l2 += __shfl_xor(l2, 32);
        int q = qbase + 16 * u + cl;
        if (q < NF) {
            if (quad == 0) lsp[lb + q] = l2;
            float* pr = Opr + ob + (long)q * 64;
            float* pi2 = Opi + ob + (long)q * 64;
#pragma unroll
            for (int nt = 0; nt < 4; ++nt) {
                int d0 = 16 * nt + quad * 4;
                *(f32x4*)(pr + d0) = Or2[nt][u];
                *(f32x4*)(pi2 + d0) = Oi2[nt][u];
            }
        }
    }
}

extern "C" void kernel_launch(void* const* d_in, const int* in_sizes, int n_in,
                              void* d_out, int out_size, void* d_ws, size_t ws_size,
                              hipStream_t stream) {
    const float* x   = (const float*)d_in[0];
    const float* g   = (const float*)d_in[1];
    const float* be  = (const float*)d_in[2];
    const float* Wqr = (const float*)d_in[3];
    const float* bqr = (const float*)d_in[4];
    const float* Wqi = (const float*)d_in[5];
    const float* bqi = (const float*)d_in[6];
    const float* Wkr = (const float*)d_in[7];
    const float* bkr = (const float*)d_in[8];
    const float* Wki = (const float*)d_in[9];
    const float* bki = (const float*)d_in[10];
    const float* Wvr = (const float*)d_in[11];
    const float* bvr = (const float*)d_in[12];
    const float* Wvi = (const float*)d_in[13];
    const float* bvi = (const float*)d_in[14];
    const float* Wo  = (const float*)d_in[15];
    float* out = (float*)d_out;

    const long SZ_T = (long)NB * NL * NE;  // 8,388,608
    const long SZ_F = (long)NB * NF * NE;  // 4,196,352
    float2* twg = (float2*)d_ws;            // 2048 float2
    short* xnb = (short*)(twg + 2048);      // bf16 region
    short* xr  = xnb + SZ_T;
    short* xi  = xr + SZ_F;
    short* Qr  = xi + SZ_F;
    short* Qi  = Qr + SZ_F;
    short* Kr  = Qi + SZ_F;
    short* Ki  = Kr + SZ_F;
    short* Vr  = Ki + SZ_F;
    short* Vi  = Vr + SZ_F;
    short* Orb = Vi + SZ_F;                 // (unused since R6; layout kept)
    short* Oib = Orb + SZ_F;                // (unused since R6; layout kept)
    short* yt  = Oib + SZ_F;                // SZ_T bf16
    short* wb  = yt + SZ_T;                 // 7 * WSZ bf16
    float* Opr = (float*)(wb + 7L * WSZ);   // 2 halves x NB x NH x QPAD x 64 f32
    float* Opi = Opr + 2 * OPSZ;
    float* lsp = Opi + 2 * OPSZ;            // 2 x NB x NH x QPAD f32
    (void)Orb; (void)Oib;

    twiddle_kernel<<<NL / 2 / 256, 256, 0, stream>>>(twg);
    castw_kernel<<<dim3(WSZ / 1024, 7), 256, 0, stream>>>(Wqr, Wqi, Wkr, Wki, Wvr, Wvi, Wo, wb);
    ln_kernel<<<NB * NL / 4, 256, 0, stream>>>(x, g, be, xnb);
    rfft_pair<<<NB * 256, 256, 0, stream>>>(xnb, twg, xr, xi);
    int Nf = NB * NF;                       // 8196
    dim3 gq(NE / 128, (Nf + 127) / 128, 6);
    gemm_qkv<<<gq, 256, 0, stream>>>(xr, xi, wb, bqr, bqi, bkr, bki, bvr, bvi,
                                     Qr, Qi, Kr, Ki, Vr, Vi, Nf);
    fattn_mfma<<<dim3(17, NH, NB * 2), 256, 0, stream>>>(Qr, Qi, Kr, Ki, Vr, Vi, Opr, Opi, lsp);
    irfft_pair<<<NB * 256, 256, 0, stream>>>(Opr, Opi, lsp, twg, yt);
    gemm_out<<<dim3(NE / 128, NB * NL / 128), 256, 0, stream>>>(yt, wb + 6L * WSZ, out, NB * NL);
}